// Round 10
// baseline (543.582 us; speedup 1.0000x reference)
//
#include <hip/hip_runtime.h>
#include <stdint.h>

#define N_ROWS 131072
#define DIM 64
#define KB 2048
#define M_ELEMS 8388608  // N_ROWS*DIM

// ---- output offsets (float32 elements, concatenated in return order) ----
#define O_XL   0
#define O_XD   131072
#define O_CL   8519680
#define O_FIT  8519681
#define O_PRE  8519682
#define O_ENT  8519683
#define O_USED 8519684
#define O_UTOT 8519685
#define O_DK   8519686
#define O_NK   8519687
#define O_NKS  8650759
#define O_NKE  8781831

// ---- workspace byte offsets (stay <= 5267616, proven in r1) ----
#define A_DBL   0         // doubles: [0]=sumS,[1]=sumQ,[2]=sum cl,[4]=dk acc
#define A_CNT   64        // rescan counter (int)
#define A_KK2N  128       // 2048 f32 : -0.5*|k|^2
#define A_KH    8320      // 2048*64 bf16
#define A_KL    270464    // 2048*64 bf16
#define A_XLI   532608    // 131072 i32
#define A_KCNT  1056896   // 2048 i32
#define A_BCUR  1065088   // 2048 u32 (adjacent to KCNT: one memset)
#define A_KRAND 1073280   // 131072 f32
#define A_BOFF  1597568   // 2048 u32
#define A_FLAG  1605760   // 131072 u32 (dead after k_rescan)
#define A_ROWL  2130048   // 131072 u32 (dead after k_segsum)
#define A_KS64  2654336   // 131072 f64 (1 MB, live until k_elem)
// RNG phase overlays FLAG/ROWL (temporally disjoint):
#define A_BITS  1605760   // 131072 u32 (overlays FLAG)
#define A_PKEY  2130048   // 131072 u32 (overlays ROWL)
#define A_HIST  3702912   // 32768 u32
#define A_BSUM  3833984   // 128 u32 (pad 512)
#define A_CUR   3834496   // 32768 u32   [HIST..CUR contiguous: one memset 262656]
#define A_PIDX  3965568   // 131072 u32
#define A_RES1  4489856   // 131072 u32
#define WS_END  5014144   // < 5267616 ok

typedef short bf16x8 __attribute__((ext_vector_type(8)));
typedef float f32x4 __attribute__((ext_vector_type(4)));

// ======================= helpers =======================

__device__ __forceinline__ float block_reduce_sum(float v, float* lds) {
  #pragma unroll
  for (int off = 32; off > 0; off >>= 1) v += __shfl_down(v, off, 64);
  int lane = threadIdx.x & 63, wid = threadIdx.x >> 6;
  if (lane == 0) lds[wid] = v;
  __syncthreads();
  float r = 0.f;
  if (threadIdx.x == 0) {
    int nw = blockDim.x >> 6;
    for (int i = 0; i < nw; ++i) r += lds[i];
  }
  __syncthreads();
  return r;  // valid on thread 0
}

__device__ __forceinline__ unsigned short f2bf_rne(float f) {
  uint32_t u = __float_as_uint(f);
  uint32_t r = u + 0x7FFFu + ((u >> 16) & 1u);
  return (unsigned short)(r >> 16);
}

#define TF_ROUND(r) do { x0 += x1; x1 = (x1 << (r)) | (x1 >> (32 - (r))); x1 ^= x0; } while (0)

__device__ __forceinline__ void threefry2x32(uint32_t k0, uint32_t k1,
                                             uint32_t c0, uint32_t c1,
                                             uint32_t& o0, uint32_t& o1) {
  uint32_t k2 = k0 ^ k1 ^ 0x1BD11BDAu;
  uint32_t x0 = c0 + k0, x1 = c1 + k1;
  TF_ROUND(13); TF_ROUND(15); TF_ROUND(26); TF_ROUND(6);
  x0 += k1; x1 += k2 + 1u;
  TF_ROUND(17); TF_ROUND(29); TF_ROUND(16); TF_ROUND(24);
  x0 += k2; x1 += k0 + 2u;
  TF_ROUND(13); TF_ROUND(15); TF_ROUND(26); TF_ROUND(6);
  x0 += k0; x1 += k1 + 3u;
  TF_ROUND(17); TF_ROUND(29); TF_ROUND(16); TF_ROUND(24);
  x0 += k1; x1 += k2 + 4u;
  TF_ROUND(13); TF_ROUND(15); TF_ROUND(26); TF_ROUND(6);
  x0 += k2; x1 += k0 + 5u;
  o0 = x0; o1 = x1;
}

// ======================= codebook prep (knorm + decomp fused) ==============
// one wave per code row
__global__ __launch_bounds__(256) void k_prep(
    const float* __restrict__ k, unsigned short* __restrict__ kh,
    unsigned short* __restrict__ kl, float* __restrict__ kk2n) {
  int w = (blockIdx.x * blockDim.x + threadIdx.x) >> 6;  // 2048 waves
  int lane = threadIdx.x & 63;
  float v = k[(size_t)w * DIM + lane];
  unsigned short h = f2bf_rne(v);
  float hf = __uint_as_float((uint32_t)h << 16);
  kh[(size_t)w * DIM + lane] = h;
  kl[(size_t)w * DIM + lane] = f2bf_rne(v - hf);
  float q = v * v;
  #pragma unroll
  for (int off = 32; off > 0; off >>= 1) q += __shfl_down(q, off, 64);
  if (lane == 0) kk2n[w] = -0.5f * q;
}

// ======================= MFMA argmin (g=2, 1024 blocks) =====================
// S^T[code][xrow] = dot(k_code, x_row) - 0.5|k_code|^2, split-bf16.
// Folds in: prenorm sum/sumsq, xli write, tie-flag append.
__global__ __launch_bounds__(256) void k_main(
    const float* __restrict__ x, const unsigned short* __restrict__ kh,
    const unsigned short* __restrict__ kl, const float* __restrict__ kk2n,
    int* __restrict__ xli, uint32_t* __restrict__ flag, int* __restrict__ cnt,
    double* __restrict__ dbl) {
  __shared__ float lds[8];
  int lane = threadIdx.x & 63;
  int wid = threadIdx.x >> 6;
  int lrow = lane & 15;
  int lk = lane >> 4;          // 0..3
  int lbase = lk * 4;
  int r0 = (blockIdx.x * 4 + wid) * 32;   // 32 rows per wave

  bf16x8 xh[2][2], xl[2][2];
  float s_acc = 0.f, q_acc = 0.f;
  #pragma unroll
  for (int g = 0; g < 2; ++g) {
    #pragma unroll
    for (int kt = 0; kt < 2; ++kt) {
      const float* xp = x + (size_t)(r0 + g * 16 + lrow) * DIM + kt * 32 + lk * 8;
      float4 v0 = *(const float4*)xp;
      float4 v1 = *(const float4*)(xp + 4);
      float vv[8] = {v0.x, v0.y, v0.z, v0.w, v1.x, v1.y, v1.z, v1.w};
      #pragma unroll
      for (int i = 0; i < 8; ++i) {
        float v = vv[i];
        s_acc += v;
        q_acc = fmaf(v, v, q_acc);
        unsigned short h = f2bf_rne(v);
        float hf = __uint_as_float((uint32_t)h << 16);
        xh[g][kt][i] = (short)h;
        xl[g][kt][i] = (short)f2bf_rne(v - hf);
      }
    }
  }
  // prenorm partial sums (each x element loaded exactly once grid-wide)
  float bs = block_reduce_sum(s_acc, lds);
  float bq = block_reduce_sum(q_acc, lds);
  if (threadIdx.x == 0) {
    atomicAdd(&dbl[0], (double)bs);
    atomicAdd(&dbl[1], (double)bq);
  }

  float b1[2], b2[2];
  uint32_t j1[2];
  #pragma unroll
  for (int g = 0; g < 2; ++g) { b1[g] = -3.402823466e38f; b2[g] = -3.402823466e38f; j1[g] = 0; }

  for (int t = 0; t < KB / 16; ++t) {
    int c0 = t * 16;
    size_t abase = (size_t)(c0 + lrow) * DIM + lk * 8;
    bf16x8 ah0 = *(const bf16x8*)(kh + abase);
    bf16x8 ah1 = *(const bf16x8*)(kh + abase + 32);
    bf16x8 al0 = *(const bf16x8*)(kl + abase);
    bf16x8 al1 = *(const bf16x8*)(kl + abase + 32);
    f32x4 kkv = *(const f32x4*)(kk2n + c0 + lbase);
    uint32_t jb = (uint32_t)(c0 + lbase);
    #pragma unroll
    for (int g = 0; g < 2; ++g) {
      f32x4 acc = __builtin_amdgcn_mfma_f32_16x16x32_bf16(ah0, xh[g][0], kkv, 0, 0, 0);
      acc = __builtin_amdgcn_mfma_f32_16x16x32_bf16(ah1, xh[g][1], acc, 0, 0, 0);
      acc = __builtin_amdgcn_mfma_f32_16x16x32_bf16(al0, xh[g][0], acc, 0, 0, 0);
      acc = __builtin_amdgcn_mfma_f32_16x16x32_bf16(al1, xh[g][1], acc, 0, 0, 0);
      acc = __builtin_amdgcn_mfma_f32_16x16x32_bf16(ah0, xl[g][0], acc, 0, 0, 0);
      acc = __builtin_amdgcn_mfma_f32_16x16x32_bf16(ah1, xl[g][1], acc, 0, 0, 0);
      #pragma unroll
      for (int reg = 0; reg < 4; ++reg) {
        float v = acc[reg];
        bool gt = v > b1[g];
        float mn = fminf(v, b1[g]);
        b2[g] = fmaxf(b2[g], mn);
        b1[g] = gt ? v : b1[g];
        j1[g] = gt ? (jb + (uint32_t)reg) : j1[g];
      }
    }
  }

  // merge the 4 lanes (lane^16, lane^32) sharing one x-row; then epilogue
  #pragma unroll
  for (int g = 0; g < 2; ++g) {
    #pragma unroll
    for (int s = 16; s <= 32; s <<= 1) {
      float ob1 = __shfl_xor(b1[g], s, 64);
      float ob2 = __shfl_xor(b2[g], s, 64);
      uint32_t oj1 = __shfl_xor(j1[g], s, 64);
      bool gt = ob1 > b1[g];
      float mn = fminf(b1[g], ob1);
      b2[g] = fmaxf(fmaxf(b2[g], ob2), mn);
      b1[g] = fmaxf(b1[g], ob1);
      j1[g] = gt ? oj1 : j1[g];
    }
    if (lk == 0) {
      int row = r0 + g * 16 + lrow;
      xli[row] = (int)j1[g];
      if (b1[g] - b2[g] < 0.01f) {  // score gap = dist gap / 2
        int i = atomicAdd(cnt, 1);
        flag[i] = (uint32_t)row;
      }
    }
  }
}

// exact fp64 full rescan for near-tie rows; one wave per row
__global__ __launch_bounds__(256) void k_rescan(
    const uint32_t* __restrict__ flag, const int* __restrict__ cnt,
    const float* __restrict__ x, const float* __restrict__ k,
    int* __restrict__ xli) {
  __shared__ float xs[4][64];
  int lane = threadIdx.x & 63;
  int wid = threadIdx.x >> 6;
  int gw = (blockIdx.x * blockDim.x + threadIdx.x) >> 6;
  int n = *cnt;
  for (int fi = gw; fi < n; fi += 1024) {
    int row = flag[fi];
    xs[wid][lane] = x[(size_t)row * DIM + lane];  // wave-synchronous LDS
    double bd = 1e300;
    int bj = 0;
    for (int j = lane; j < KB; j += 64) {
      const float* kr = k + (size_t)j * DIM;
      double e = 0.0;
      #pragma unroll
      for (int d = 0; d < DIM; ++d) {
        double diff = (double)xs[wid][d] - (double)kr[d];
        e = fma(diff, diff, e);
      }
      if (e < bd) { bd = e; bj = j; }
    }
    #pragma unroll
    for (int off = 32; off > 0; off >>= 1) {
      double od = __shfl_down(bd, off, 64);
      int oj = __shfl_down(bj, off, 64);
      if (od < bd || (od == bd && oj < bj)) { bd = od; bj = oj; }
    }
    if (lane == 0) xli[row] = bj;
  }
}

// exact kcnt histogram, built AFTER rescan corrections
__global__ void k_hist_rows(const int* __restrict__ xli, int* __restrict__ kcnt) {
  int i = blockIdx.x * blockDim.x + threadIdx.x;
  atomicAdd(&kcnt[xli[i]], 1);
}

__global__ __launch_bounds__(256) void k_finish(
    const float* __restrict__ x, const float* __restrict__ k,
    const int* __restrict__ xli, float* __restrict__ out,
    double* __restrict__ dbl) {
  __shared__ float lds[8];
  int row = blockIdx.x * blockDim.x + threadIdx.x;
  int j = xli[row];
  out[O_XL + row] = (float)j;
  const float4* xp = (const float4*)(x + (size_t)row * DIM);
  const float4* kp = (const float4*)(k + (size_t)j * DIM);
  float4* xd = (float4*)(out + O_XD + (size_t)row * DIM);
  float a = 0.f, b = 0.f, c = 0.f, d = 0.f;
  #pragma unroll
  for (int q = 0; q < 16; ++q) {
    float4 kv = kp[q];
    float4 xv = xp[q];
    xd[q] = kv;
    float dx = kv.x - xv.x, dy = kv.y - xv.y;
    float dz = kv.z - xv.z, dw = kv.w - xv.w;
    a = fmaf(dx, dx, a); b = fmaf(dy, dy, b);
    c = fmaf(dz, dz, c); d = fmaf(dw, dw, d);
  }
  float cl = (a + b) + (c + d);    // == min dist (fit & commit share this)
  float bc = block_reduce_sum(cl, lds);
  if (threadIdx.x == 0) atomicAdd(&dbl[2], (double)bc);
}

// ======================= segment sum via counting sort =======================

__global__ __launch_bounds__(1024) void k_scan_bins(const int* __restrict__ kcnt,
                                                    uint32_t* __restrict__ boffs) {
  __shared__ uint32_t part[1024];
  int tid = threadIdx.x;
  uint32_t c0 = (uint32_t)kcnt[2 * tid];
  uint32_t c1 = (uint32_t)kcnt[2 * tid + 1];
  part[tid] = c0 + c1;
  __syncthreads();
  for (int off = 1; off < 1024; off <<= 1) {
    uint32_t v = (tid >= off) ? part[tid - off] : 0u;
    __syncthreads();
    part[tid] += v;
    __syncthreads();
  }
  uint32_t run = (tid > 0) ? part[tid - 1] : 0u;
  boffs[2 * tid] = run;
  boffs[2 * tid + 1] = run + c0;
}

__global__ void k_scatter_rows(const int* __restrict__ xli, const uint32_t* __restrict__ boffs,
                               uint32_t* __restrict__ bcur, uint32_t* __restrict__ rowlist) {
  int i = blockIdx.x * blockDim.x + threadIdx.x;
  int b = xli[i];
  uint32_t pos = boffs[b] + atomicAdd(&bcur[b], 1u);
  rowlist[pos] = (uint32_t)i;
}

// equal-work segment sum: one wave per 16 rowlist positions; lane = dim column.
__global__ __launch_bounds__(256) void k_segsum(
    const uint32_t* __restrict__ rowlist, const int* __restrict__ xli,
    const float* __restrict__ x, double* __restrict__ ks64) {
  int gw = (blockIdx.x * blockDim.x + threadIdx.x) >> 6;  // 8192 waves
  int lane = threadIdx.x & 63;
  uint32_t p0 = (uint32_t)gw * 16;
  double acc = 0.0;
  int cur = -1;
  #pragma unroll 4
  for (int i = 0; i < 16; ++i) {
    uint32_t row = rowlist[p0 + i];
    int bin = xli[row];
    if (bin != cur) {
      if (cur >= 0) atomicAdd(&ks64[(size_t)cur * DIM + lane], acc);
      acc = 0.0; cur = bin;
    }
    acc += (double)x[(size_t)row * DIM + lane];
  }
  if (cur >= 0) atomicAdd(&ks64[(size_t)cur * DIM + lane], acc);
}

// ---- JAX threefry permutation replication (15-bit bucket sort ×2) ----

__global__ void k_bits_hist(int which, uint32_t* __restrict__ bits,
                            uint32_t* __restrict__ hist) {
  uint32_t a0, a1, b0, b1;
  threefry2x32(0u, 42u, 0u, 2u, a0, b0);
  threefry2x32(0u, 42u, 1u, 3u, a1, b1);
  uint32_t k0, k1;
  if (which == 0) { k0 = b0; k1 = b1; }
  else {
    uint32_t c0, c1, d0, d1;
    threefry2x32(a0, a1, 0u, 2u, c0, d0);
    threefry2x32(a0, a1, 1u, 3u, c1, d1);
    k0 = d0; k1 = d1;
  }
  int i = blockIdx.x * blockDim.x + threadIdx.x;  // 65536 threads
  uint32_t y0, y1;
  threefry2x32(k0, k1, (uint32_t)i, (uint32_t)(i + 65536), y0, y1);
  bits[i] = y0;
  bits[i + 65536] = y1;
  atomicAdd(&hist[y0 >> 17], 1u);
  atomicAdd(&hist[y1 >> 17], 1u);
}

// local exclusive scan of 256 bins per block; in-place; block total -> bsum
__global__ __launch_bounds__(256) void k_scanA(uint32_t* __restrict__ hist,
                                               uint32_t* __restrict__ bsum) {
  __shared__ uint32_t sh[256];
  int tid = threadIdx.x;
  int bin = blockIdx.x * 256 + tid;
  uint32_t v = hist[bin];
  sh[tid] = v;
  __syncthreads();
  for (int off = 1; off < 256; off <<= 1) {
    uint32_t t = (tid >= off) ? sh[tid - off] : 0u;
    __syncthreads();
    sh[tid] += t;
    __syncthreads();
  }
  hist[bin] = sh[tid] - v;                 // exclusive local prefix
  if (tid == 255) bsum[blockIdx.x] = sh[tid];
}

__global__ void k_scanB(uint32_t* __restrict__ bsum) {  // 1 block, 128 threads
  __shared__ uint32_t sh[128];
  int tid = threadIdx.x;
  uint32_t v = bsum[tid];
  sh[tid] = v;
  __syncthreads();
  for (int off = 1; off < 128; off <<= 1) {
    uint32_t t = (tid >= off) ? sh[tid - off] : 0u;
    __syncthreads();
    sh[tid] += t;
    __syncthreads();
  }
  bsum[tid] = sh[tid] - v;  // exclusive
}

__global__ void k_scatter(const uint32_t* __restrict__ bits, const uint32_t* __restrict__ hist,
                          const uint32_t* __restrict__ bsum, uint32_t* __restrict__ cursor,
                          uint32_t* __restrict__ pkey, uint32_t* __restrict__ pidx) {
  int i = blockIdx.x * blockDim.x + threadIdx.x;
  uint32_t key = bits[i];
  uint32_t bin = key >> 17;
  uint32_t pos = hist[bin] + bsum[bin >> 8] + atomicAdd(&cursor[bin], 1u);
  pkey[pos] = key; pidx[pos] = (uint32_t)i;
}

// rank within bucket (stable). limit==0: write full res; else write first
// `limit` positions of the final permutation AND gather x rows into krand.
__global__ void k_rank(const uint32_t* __restrict__ pkey, const uint32_t* __restrict__ pidx,
                       const uint32_t* __restrict__ hist, const uint32_t* __restrict__ bsum,
                       const uint32_t* __restrict__ cursor,
                       const uint32_t* __restrict__ srcvals, uint32_t* __restrict__ outv,
                       const float* __restrict__ x, float* __restrict__ krand,
                       int limit) {
  int s = blockIdx.x * blockDim.x + threadIdx.x;
  uint32_t myk = pkey[s], myi = pidx[s];
  uint32_t bin = myk >> 17;
  uint32_t start = hist[bin] + bsum[bin >> 8], cntb = cursor[bin];
  uint32_t r = 0;
  for (uint32_t t = 0; t < cntb; ++t) {
    uint32_t ok = pkey[start + t], oi = pidx[start + t];
    r += (ok < myk || (ok == myk && oi < myi)) ? 1u : 0u;
  }
  uint32_t pos = start + r;
  if (limit == 0) {
    outv[pos] = myi;   // res1[i] = original index at round-1 sorted position i
  } else if (pos < (uint32_t)limit) {
    uint32_t orig = srcvals[myi];      // final perm value
    const float4* xs = (const float4*)(x + (size_t)orig * DIM);
    float4* kd = (float4*)(krand + (size_t)pos * DIM);
    #pragma unroll
    for (int q = 0; q < 16; ++q) kd[q] = xs[q];
  }
}

// ======================= EMA update + finale =======================

__global__ __launch_bounds__(256) void k_elem_kernel(
    const double* __restrict__ ks64, const int* __restrict__ kcnt,
    const float* __restrict__ k_sum_in, const float* __restrict__ k_elem_in,
    const float* __restrict__ k_in, const float* __restrict__ krand,
    float* __restrict__ out, double* __restrict__ dbl) {
  __shared__ float lds[8];
  const float OMF = (float)(1.0 - 0.99);
  int e = blockIdx.x * blockDim.x + threadIdx.x;
  int b = e >> 6;
  float part = (float)ks64[e];
  float nks = 0.99f * k_sum_in[e] + OMF * part;
  out[O_NKS + e] = nks;
  float cnt = (float)kcnt[b];
  float ke = 0.99f * k_elem_in[b] + OMF * cnt;
  float nk = (ke >= 1.f) ? (nks / ke) : krand[e];
  out[O_NK + e] = nk;
  float dd = nk - k_in[e];
  float bsum = block_reduce_sum(dd * dd, lds);
  if (threadIdx.x == 0) atomicAdd(&dbl[4], (double)bsum);
}

__global__ __launch_bounds__(1024) void k_finale(
    const int* __restrict__ kcnt, const float* __restrict__ k_elem_in,
    float* __restrict__ out, const double* __restrict__ dbl) {
  __shared__ float ent_l[1024];
  __shared__ int u1_l[1024], u2_l[1024];
  const float OMF = (float)(1.0 - 0.99);
  int tid = threadIdx.x;
  float ent = 0.f; int used = 0, usage = 0;
  #pragma unroll
  for (int t = 0; t < 2; ++t) {
    int b = tid + t * 1024;
    float cnt = (float)kcnt[b];
    float ke = 0.99f * k_elem_in[b] + OMF * cnt;
    out[O_NKE + b] = ke;
    float p = cnt * (1.f / 131072.f);
    ent -= p * logf(p + 1e-8f);
    used += (cnt >= 1.f) ? 1 : 0;
    usage += (ke >= 1.f) ? 1 : 0;
  }
  ent_l[tid] = ent; u1_l[tid] = used; u2_l[tid] = usage;
  __syncthreads();
  for (int off = 512; off > 0; off >>= 1) {
    if (tid < off) {
      ent_l[tid] += ent_l[tid + off];
      u1_l[tid] += u1_l[tid + off];
      u2_l[tid] += u2_l[tid + off];
    }
    __syncthreads();
  }
  if (tid == 0) {
    double M = (double)M_ELEMS;
    double sumS = dbl[0], sumQ = dbl[1];
    double var = (sumQ - sumS * sumS / M) / M;
    out[O_PRE] = (float)sqrt(var > 0.0 ? var : 0.0);
    out[O_FIT] = (float)(dbl[2] / (double)N_ROWS);
    out[O_CL]  = (float)(dbl[2] / M);
    out[O_DK]  = (float)sqrt(dbl[4] / (double)(KB * DIM));
    out[O_ENT] = ent_l[0];
    out[O_USED] = (float)u1_l[0];
    out[O_UTOT] = (float)u2_l[0];
  }
}

// ======================= launch =======================

extern "C" void kernel_launch(void* const* d_in, const int* in_sizes, int n_in,
                              void* d_out, int out_size, void* d_ws, size_t ws_size,
                              hipStream_t stream) {
  (void)in_sizes; (void)n_in; (void)out_size; (void)ws_size;
  const float* x      = (const float*)d_in[0];
  const float* k      = (const float*)d_in[1];
  const float* k_sum  = (const float*)d_in[2];
  const float* k_elem = (const float*)d_in[3];
  float* out = (float*)d_out;
  char* ws = (char*)d_ws;

  double*   dbl   = (double*)(ws + A_DBL);
  int*      cnt   = (int*)(ws + A_CNT);
  float*    kk2n  = (float*)(ws + A_KK2N);
  unsigned short* kh = (unsigned short*)(ws + A_KH);
  unsigned short* kl = (unsigned short*)(ws + A_KL);
  int*      xli   = (int*)(ws + A_XLI);
  int*      kcnt  = (int*)(ws + A_KCNT);
  uint32_t* bcur  = (uint32_t*)(ws + A_BCUR);
  float*    krand = (float*)(ws + A_KRAND);
  uint32_t* boffs = (uint32_t*)(ws + A_BOFF);
  uint32_t* flag  = (uint32_t*)(ws + A_FLAG);
  uint32_t* rowl  = (uint32_t*)(ws + A_ROWL);
  double*   ks64  = (double*)(ws + A_KS64);
  uint32_t* bits  = (uint32_t*)(ws + A_BITS);
  uint32_t* pkey  = (uint32_t*)(ws + A_PKEY);
  uint32_t* hist  = (uint32_t*)(ws + A_HIST);
  uint32_t* bsum  = (uint32_t*)(ws + A_BSUM);
  uint32_t* cur   = (uint32_t*)(ws + A_CUR);
  uint32_t* pidx  = (uint32_t*)(ws + A_PIDX);
  uint32_t* res1  = (uint32_t*)(ws + A_RES1);

  (void)hipMemsetAsync(ws + A_DBL, 0, 128, stream);        // dbl + cnt
  (void)hipMemsetAsync(ws + A_KCNT, 0, 16384, stream);     // kcnt + bcur
  (void)hipMemsetAsync(ws + A_KS64, 0, 1048576, stream);   // f64 accumulators

  k_prep<<<512, 256, 0, stream>>>(k, kh, kl, kk2n);
  k_main<<<1024, 256, 0, stream>>>(x, kh, kl, kk2n, xli, flag, cnt, dbl);
  k_rescan<<<256, 256, 0, stream>>>(flag, cnt, x, k, xli);
  k_finish<<<512, 256, 0, stream>>>(x, k, xli, out, dbl);

  // segment sum via counting sort + equal-work chunked accumulation
  k_hist_rows<<<512, 256, 0, stream>>>(xli, kcnt);
  k_scan_bins<<<1, 1024, 0, stream>>>(kcnt, boffs);
  k_scatter_rows<<<512, 256, 0, stream>>>(xli, boffs, bcur, rowl);
  k_segsum<<<2048, 256, 0, stream>>>(rowl, xli, x, ks64);

  // jax.random.permutation(key(42), 131072): 2 stable sort rounds
  (void)hipMemsetAsync(ws + A_HIST, 0, 262656, stream);    // hist + bsum + cur
  k_bits_hist<<<256, 256, 0, stream>>>(0, bits, hist);
  k_scanA<<<128, 256, 0, stream>>>(hist, bsum);
  k_scanB<<<1, 128, 0, stream>>>(bsum);
  k_scatter<<<512, 256, 0, stream>>>(bits, hist, bsum, cur, pkey, pidx);
  k_rank<<<512, 256, 0, stream>>>(pkey, pidx, hist, bsum, cur, nullptr, res1,
                                  nullptr, nullptr, 0);
  (void)hipMemsetAsync(ws + A_HIST, 0, 262656, stream);
  k_bits_hist<<<256, 256, 0, stream>>>(1, bits, hist);
  k_scanA<<<128, 256, 0, stream>>>(hist, bsum);
  k_scanB<<<1, 128, 0, stream>>>(bsum);
  k_scatter<<<512, 256, 0, stream>>>(bits, hist, bsum, cur, pkey, pidx);
  k_rank<<<512, 256, 0, stream>>>(pkey, pidx, hist, bsum, cur, res1, nullptr,
                                  x, krand, 2048);

  k_elem_kernel<<<512, 256, 0, stream>>>(ks64, kcnt, k_sum, k_elem, k, krand, out, dbl);
  k_finale<<<1, 1024, 0, stream>>>(kcnt, k_elem, out, dbl);
}

// Round 11
// 392.486 us; speedup vs baseline: 1.3850x; 1.3850x over previous
//
#include <hip/hip_runtime.h>
#include <stdint.h>

#define N_ROWS 131072
#define DIM 64
#define KB 2048
#define M_ELEMS 8388608  // N_ROWS*DIM

// ---- output offsets (float32 elements, concatenated in return order) ----
#define O_XL   0
#define O_XD   131072
#define O_CL   8519680
#define O_FIT  8519681
#define O_PRE  8519682
#define O_ENT  8519683
#define O_USED 8519684
#define O_UTOT 8519685
#define O_DK   8519686
#define O_NK   8519687
#define O_NKS  8650759
#define O_NKE  8781831

// ---- workspace byte offsets (stay <= 5267616, proven in r1) ----
#define A_DBL   0         // doubles: [0]=sumS,[1]=sumQ,[2]=sum cl,[4]=dk acc
#define A_CNT   64        // rescan counter (int)
#define A_KK2N  128       // 2048 f32 : -0.5*|k|^2
#define A_KST   8320      // 524288 B: pre-swizzled kh|kl tile images (128 tiles x 4096 B)
#define A_XLI   532608    // 131072 i32
#define A_KCNT  1056896   // 2048 i32
#define A_BCUR  1065088   // 2048 u32 (adjacent to KCNT: one memset)
#define A_KRAND 1073280   // 131072 f32
#define A_BOFF  1597568   // 2048 u32
#define A_FLAG  1605760   // 131072 u32 (dead after k_rescan)
#define A_ROWL  2130048   // 131072 u32 (dead after k_segsum)
#define A_KS64  2654336   // 131072 f64 (1 MB, live until k_elem)
// RNG phase overlays FLAG/ROWL (temporally disjoint):
#define A_BITS  1605760   // 131072 u32 (overlays FLAG)
#define A_PKEY  2130048   // 131072 u32 (overlays ROWL)
#define A_HIST  3702912   // 32768 u32
#define A_BSUM  3833984   // 128 u32 (pad 512)
#define A_CUR   3834496   // 32768 u32   [HIST..CUR contiguous: one memset 262656]
#define A_PIDX  3965568   // 131072 u32
#define A_RES1  4489856   // 131072 u32
#define WS_END  5014144   // < 5267616 ok

typedef short bf16x8 __attribute__((ext_vector_type(8)));
typedef float f32x4 __attribute__((ext_vector_type(4)));

#define GLL16(G, L) __builtin_amdgcn_global_load_lds( \
    (const __attribute__((address_space(1))) void*)(G), \
    (__attribute__((address_space(3))) void*)(L), 16, 0, 0)
#define GLL4(G, L) __builtin_amdgcn_global_load_lds( \
    (const __attribute__((address_space(1))) void*)(G), \
    (__attribute__((address_space(3))) void*)(L), 4, 0, 0)

// ======================= helpers =======================

__device__ __forceinline__ float block_reduce_sum(float v, float* lds) {
  #pragma unroll
  for (int off = 32; off > 0; off >>= 1) v += __shfl_down(v, off, 64);
  int lane = threadIdx.x & 63, wid = threadIdx.x >> 6;
  if (lane == 0) lds[wid] = v;
  __syncthreads();
  float r = 0.f;
  if (threadIdx.x == 0) {
    int nw = blockDim.x >> 6;
    for (int i = 0; i < nw; ++i) r += lds[i];
  }
  __syncthreads();
  return r;  // valid on thread 0
}

__device__ __forceinline__ unsigned short f2bf_rne(float f) {
  uint32_t u = __float_as_uint(f);
  uint32_t r = u + 0x7FFFu + ((u >> 16) & 1u);
  return (unsigned short)(r >> 16);
}

#define TF_ROUND(r) do { x0 += x1; x1 = (x1 << (r)) | (x1 >> (32 - (r))); x1 ^= x0; } while (0)

__device__ __forceinline__ void threefry2x32(uint32_t k0, uint32_t k1,
                                             uint32_t c0, uint32_t c1,
                                             uint32_t& o0, uint32_t& o1) {
  uint32_t k2 = k0 ^ k1 ^ 0x1BD11BDAu;
  uint32_t x0 = c0 + k0, x1 = c1 + k1;
  TF_ROUND(13); TF_ROUND(15); TF_ROUND(26); TF_ROUND(6);
  x0 += k1; x1 += k2 + 1u;
  TF_ROUND(17); TF_ROUND(29); TF_ROUND(16); TF_ROUND(24);
  x0 += k2; x1 += k0 + 2u;
  TF_ROUND(13); TF_ROUND(15); TF_ROUND(26); TF_ROUND(6);
  x0 += k0; x1 += k1 + 3u;
  TF_ROUND(17); TF_ROUND(29); TF_ROUND(16); TF_ROUND(24);
  x0 += k1; x1 += k2 + 4u;
  TF_ROUND(13); TF_ROUND(15); TF_ROUND(26); TF_ROUND(6);
  x0 += k2; x1 += k0 + 5u;
  o0 = x0; o1 = x1;
}

// ======================= codebook prep =======================
// one wave per code row. Writes the PRE-SWIZZLED kh|kl tile image so that
// a linear global_load_lds produces bank-spread ds_read_b128 fragments:
// tile t (4096 B) = [kh 2048 B | kl 2048 B]; within each half, (code r, dim d)
// lives at byte r*128 + (((d>>3) ^ (r&7))<<4) + (d&7)*2.
__global__ __launch_bounds__(256) void k_prep(
    const float* __restrict__ k, unsigned short* __restrict__ kst,
    float* __restrict__ kk2n) {
  int w = (blockIdx.x * blockDim.x + threadIdx.x) >> 6;  // code j, 2048 waves
  int lane = threadIdx.x & 63;                           // dim d
  float v = k[(size_t)w * DIM + lane];
  unsigned short h = f2bf_rne(v);
  float hf = __uint_as_float((uint32_t)h << 16);
  unsigned short lo = f2bf_rne(v - hf);
  int t = w >> 4, r = w & 15;
  int c = lane >> 3, e = lane & 7;
  int slot = c ^ (r & 7);
  size_t u16i = (size_t)t * 2048 + r * 64 + slot * 8 + e;
  kst[u16i] = h;           // kh half
  kst[u16i + 1024] = lo;   // kl half (+2048 B)
  float q = v * v;
  #pragma unroll
  for (int off = 32; off > 0; off >>= 1) q += __shfl_down(q, off, 64);
  if (lane == 0) kk2n[w] = -0.5f * q;
}

// ======================= MFMA argmin (LDS-staged k) ========================
// 512 threads = 8 waves, g=2 (32 rows/wave, 256 rows/block), 512 blocks.
// Per 16-code tile: block stages 4 KB frags + 64 B kk ONCE into LDS
// (double-buffered), all 8 waves consume. Folds in prenorm, xli, tie-flag.
__global__ __launch_bounds__(512) void k_main(
    const float* __restrict__ x, const unsigned short* __restrict__ kst,
    const float* __restrict__ kk2n,
    int* __restrict__ xli, uint32_t* __restrict__ flag, int* __restrict__ cnt,
    double* __restrict__ dbl) {
  __shared__ __align__(16) char smem[8704];   // 2 x (4096 frag + 256 kk)
  __shared__ float lds_red[8];
  int lane = threadIdx.x & 63;
  int wid = threadIdx.x >> 6;   // 0..7
  int lrow = lane & 15;
  int lk = lane >> 4;           // 0..3
  int r0 = (blockIdx.x * 8 + wid) * 32;

  // load + decompose x fragments: 2 row-groups x 2 K-halves
  bf16x8 xh[2][2], xl[2][2];
  float s_acc = 0.f, q_acc = 0.f;
  #pragma unroll
  for (int g = 0; g < 2; ++g) {
    #pragma unroll
    for (int kt = 0; kt < 2; ++kt) {
      const float* xp = x + (size_t)(r0 + g * 16 + lrow) * DIM + kt * 32 + lk * 8;
      float4 v0 = *(const float4*)xp;
      float4 v1 = *(const float4*)(xp + 4);
      float vv[8] = {v0.x, v0.y, v0.z, v0.w, v1.x, v1.y, v1.z, v1.w};
      #pragma unroll
      for (int i = 0; i < 8; ++i) {
        float v = vv[i];
        s_acc += v;
        q_acc = fmaf(v, v, q_acc);
        unsigned short h = f2bf_rne(v);
        float hf = __uint_as_float((uint32_t)h << 16);
        xh[g][kt][i] = (short)h;
        xl[g][kt][i] = (short)f2bf_rne(v - hf);
      }
    }
  }
  // prenorm partial sums (x loaded exactly once grid-wide)
  float bs = block_reduce_sum(s_acc, lds_red);
  float bq = block_reduce_sum(q_acc, lds_red);
  if (threadIdx.x == 0) {
    atomicAdd(&dbl[0], (double)bs);
    atomicAdd(&dbl[1], (double)bq);
  }

  // loop-invariant swizzled fragment byte offsets
  int offH0 = lrow * 128 + (((lk    ) ^ (lrow & 7)) << 4);
  int offH1 = lrow * 128 + (((lk + 4) ^ (lrow & 7)) << 4);

  const char* kst_b = (const char*)kst;
  const char* kk_b  = (const char*)kk2n;

  // prologue: stage tile 0 into buffer 0
  if (wid < 4) GLL16(kst_b + (size_t)wid * 1024 + (size_t)lane * 16, smem + wid * 1024);
  else if (wid == 4) GLL4(kk_b + (size_t)(lane & 15) * 4, smem + 4096);

  float b1[2], b2[2];
  uint32_t j1[2];
  #pragma unroll
  for (int g = 0; g < 2; ++g) { b1[g] = -3.402823466e38f; b2[g] = -3.402823466e38f; j1[g] = 0; }

  for (int t = 0; t < KB / 16; ++t) {
    char* B  = smem + (t & 1) * 4352;
    char* Bn = smem + ((t + 1) & 1) * 4352;
    if (t + 1 < KB / 16) {
      if (wid < 4)
        GLL16(kst_b + (size_t)(t + 1) * 4096 + (size_t)wid * 1024 + (size_t)lane * 16,
              Bn + wid * 1024);
      else if (wid == 4)
        GLL4(kk_b + (size_t)(t + 1) * 64 + (size_t)(lane & 15) * 4, Bn + 4096);
    }
    __syncthreads();   // drains vmcnt -> tile t (and t+1) resident in LDS

    bf16x8 ah0 = *(const bf16x8*)(B + offH0);
    bf16x8 ah1 = *(const bf16x8*)(B + offH1);
    bf16x8 al0 = *(const bf16x8*)(B + 2048 + offH0);
    bf16x8 al1 = *(const bf16x8*)(B + 2048 + offH1);
    f32x4 kkv  = *(const f32x4*)(B + 4096 + lk * 16);
    uint32_t jb = (uint32_t)(t * 16 + lk * 4);
    #pragma unroll
    for (int g = 0; g < 2; ++g) {
      f32x4 acc = __builtin_amdgcn_mfma_f32_16x16x32_bf16(ah0, xh[g][0], kkv, 0, 0, 0);
      acc = __builtin_amdgcn_mfma_f32_16x16x32_bf16(ah1, xh[g][1], acc, 0, 0, 0);
      acc = __builtin_amdgcn_mfma_f32_16x16x32_bf16(al0, xh[g][0], acc, 0, 0, 0);
      acc = __builtin_amdgcn_mfma_f32_16x16x32_bf16(al1, xh[g][1], acc, 0, 0, 0);
      acc = __builtin_amdgcn_mfma_f32_16x16x32_bf16(ah0, xl[g][0], acc, 0, 0, 0);
      acc = __builtin_amdgcn_mfma_f32_16x16x32_bf16(ah1, xl[g][1], acc, 0, 0, 0);
      #pragma unroll
      for (int reg = 0; reg < 4; ++reg) {
        float v = acc[reg];
        bool gt = v > b1[g];
        float mn = fminf(v, b1[g]);
        b2[g] = fmaxf(b2[g], mn);
        b1[g] = gt ? v : b1[g];
        j1[g] = gt ? (jb + (uint32_t)reg) : j1[g];
      }
    }
    __syncthreads();   // protect buffer before next overwrite
  }

  // merge the 4 lanes (lane^16, lane^32) sharing one x-row; epilogue
  #pragma unroll
  for (int g = 0; g < 2; ++g) {
    #pragma unroll
    for (int s = 16; s <= 32; s <<= 1) {
      float ob1 = __shfl_xor(b1[g], s, 64);
      float ob2 = __shfl_xor(b2[g], s, 64);
      uint32_t oj1 = __shfl_xor(j1[g], s, 64);
      bool gt = ob1 > b1[g];
      float mn = fminf(b1[g], ob1);
      b2[g] = fmaxf(fmaxf(b2[g], ob2), mn);
      b1[g] = fmaxf(b1[g], ob1);
      j1[g] = gt ? oj1 : j1[g];
    }
    if (lk == 0) {
      int row = r0 + g * 16 + lrow;
      xli[row] = (int)j1[g];
      if (b1[g] - b2[g] < 0.01f) {  // score gap = dist gap / 2
        int i = atomicAdd(cnt, 1);
        flag[i] = (uint32_t)row;
      }
    }
  }
}

// exact fp64 full rescan for near-tie rows; one wave per row
__global__ __launch_bounds__(256) void k_rescan(
    const uint32_t* __restrict__ flag, const int* __restrict__ cnt,
    const float* __restrict__ x, const float* __restrict__ k,
    int* __restrict__ xli) {
  __shared__ float xs[4][64];
  int lane = threadIdx.x & 63;
  int wid = threadIdx.x >> 6;
  int gw = (blockIdx.x * blockDim.x + threadIdx.x) >> 6;
  int n = *cnt;
  for (int fi = gw; fi < n; fi += 1024) {
    int row = flag[fi];
    xs[wid][lane] = x[(size_t)row * DIM + lane];  // wave-synchronous LDS
    double bd = 1e300;
    int bj = 0;
    for (int j = lane; j < KB; j += 64) {
      const float* kr = k + (size_t)j * DIM;
      double e = 0.0;
      #pragma unroll
      for (int d = 0; d < DIM; ++d) {
        double diff = (double)xs[wid][d] - (double)kr[d];
        e = fma(diff, diff, e);
      }
      if (e < bd) { bd = e; bj = j; }
    }
    #pragma unroll
    for (int off = 32; off > 0; off >>= 1) {
      double od = __shfl_down(bd, off, 64);
      int oj = __shfl_down(bj, off, 64);
      if (od < bd || (od == bd && oj < bj)) { bd = od; bj = oj; }
    }
    if (lane == 0) xli[row] = bj;
  }
}

// exact kcnt histogram, built AFTER rescan corrections
__global__ void k_hist_rows(const int* __restrict__ xli, int* __restrict__ kcnt) {
  int i = blockIdx.x * blockDim.x + threadIdx.x;
  atomicAdd(&kcnt[xli[i]], 1);
}

__global__ __launch_bounds__(256) void k_finish(
    const float* __restrict__ x, const float* __restrict__ k,
    const int* __restrict__ xli, float* __restrict__ out,
    double* __restrict__ dbl) {
  __shared__ float lds[8];
  int row = blockIdx.x * blockDim.x + threadIdx.x;
  int j = xli[row];
  out[O_XL + row] = (float)j;
  const float4* xp = (const float4*)(x + (size_t)row * DIM);
  const float4* kp = (const float4*)(k + (size_t)j * DIM);
  float4* xd = (float4*)(out + O_XD + (size_t)row * DIM);
  float a = 0.f, b = 0.f, c = 0.f, d = 0.f;
  #pragma unroll
  for (int q = 0; q < 16; ++q) {
    float4 kv = kp[q];
    float4 xv = xp[q];
    xd[q] = kv;
    float dx = kv.x - xv.x, dy = kv.y - xv.y;
    float dz = kv.z - xv.z, dw = kv.w - xv.w;
    a = fmaf(dx, dx, a); b = fmaf(dy, dy, b);
    c = fmaf(dz, dz, c); d = fmaf(dw, dw, d);
  }
  float cl = (a + b) + (c + d);    // == min dist (fit & commit share this)
  float bc = block_reduce_sum(cl, lds);
  if (threadIdx.x == 0) atomicAdd(&dbl[2], (double)bc);
}

// ======================= segment sum via counting sort =======================

__global__ __launch_bounds__(1024) void k_scan_bins(const int* __restrict__ kcnt,
                                                    uint32_t* __restrict__ boffs) {
  __shared__ uint32_t part[1024];
  int tid = threadIdx.x;
  uint32_t c0 = (uint32_t)kcnt[2 * tid];
  uint32_t c1 = (uint32_t)kcnt[2 * tid + 1];
  part[tid] = c0 + c1;
  __syncthreads();
  for (int off = 1; off < 1024; off <<= 1) {
    uint32_t v = (tid >= off) ? part[tid - off] : 0u;
    __syncthreads();
    part[tid] += v;
    __syncthreads();
  }
  uint32_t run = (tid > 0) ? part[tid - 1] : 0u;
  boffs[2 * tid] = run;
  boffs[2 * tid + 1] = run + c0;
}

__global__ void k_scatter_rows(const int* __restrict__ xli, const uint32_t* __restrict__ boffs,
                               uint32_t* __restrict__ bcur, uint32_t* __restrict__ rowlist) {
  int i = blockIdx.x * blockDim.x + threadIdx.x;
  int b = xli[i];
  uint32_t pos = boffs[b] + atomicAdd(&bcur[b], 1u);
  rowlist[pos] = (uint32_t)i;
}

// equal-work segment sum: one wave per 16 rowlist positions; lane = dim column.
__global__ __launch_bounds__(256) void k_segsum(
    const uint32_t* __restrict__ rowlist, const int* __restrict__ xli,
    const float* __restrict__ x, double* __restrict__ ks64) {
  int gw = (blockIdx.x * blockDim.x + threadIdx.x) >> 6;  // 8192 waves
  int lane = threadIdx.x & 63;
  uint32_t p0 = (uint32_t)gw * 16;
  double acc = 0.0;
  int cur = -1;
  #pragma unroll 4
  for (int i = 0; i < 16; ++i) {
    uint32_t row = rowlist[p0 + i];
    int bin = xli[row];
    if (bin != cur) {
      if (cur >= 0) atomicAdd(&ks64[(size_t)cur * DIM + lane], acc);
      acc = 0.0; cur = bin;
    }
    acc += (double)x[(size_t)row * DIM + lane];
  }
  if (cur >= 0) atomicAdd(&ks64[(size_t)cur * DIM + lane], acc);
}

// ---- JAX threefry permutation replication (15-bit bucket sort x2) ----

__global__ void k_bits_hist(int which, uint32_t* __restrict__ bits,
                            uint32_t* __restrict__ hist) {
  uint32_t a0, a1, b0, b1;
  threefry2x32(0u, 42u, 0u, 2u, a0, b0);
  threefry2x32(0u, 42u, 1u, 3u, a1, b1);
  uint32_t k0, k1;
  if (which == 0) { k0 = b0; k1 = b1; }
  else {
    uint32_t c0, c1, d0, d1;
    threefry2x32(a0, a1, 0u, 2u, c0, d0);
    threefry2x32(a0, a1, 1u, 3u, c1, d1);
    k0 = d0; k1 = d1;
  }
  int i = blockIdx.x * blockDim.x + threadIdx.x;  // 65536 threads
  uint32_t y0, y1;
  threefry2x32(k0, k1, (uint32_t)i, (uint32_t)(i + 65536), y0, y1);
  bits[i] = y0;
  bits[i + 65536] = y1;
  atomicAdd(&hist[y0 >> 17], 1u);
  atomicAdd(&hist[y1 >> 17], 1u);
}

// local exclusive scan of 256 bins per block; in-place; block total -> bsum
__global__ __launch_bounds__(256) void k_scanA(uint32_t* __restrict__ hist,
                                               uint32_t* __restrict__ bsum) {
  __shared__ uint32_t sh[256];
  int tid = threadIdx.x;
  int bin = blockIdx.x * 256 + tid;
  uint32_t v = hist[bin];
  sh[tid] = v;
  __syncthreads();
  for (int off = 1; off < 256; off <<= 1) {
    uint32_t t = (tid >= off) ? sh[tid - off] : 0u;
    __syncthreads();
    sh[tid] += t;
    __syncthreads();
  }
  hist[bin] = sh[tid] - v;                 // exclusive local prefix
  if (tid == 255) bsum[blockIdx.x] = sh[tid];
}

__global__ void k_scanB(uint32_t* __restrict__ bsum) {  // 1 block, 128 threads
  __shared__ uint32_t sh[128];
  int tid = threadIdx.x;
  uint32_t v = bsum[tid];
  sh[tid] = v;
  __syncthreads();
  for (int off = 1; off < 128; off <<= 1) {
    uint32_t t = (tid >= off) ? sh[tid - off] : 0u;
    __syncthreads();
    sh[tid] += t;
    __syncthreads();
  }
  bsum[tid] = sh[tid] - v;  // exclusive
}

__global__ void k_scatter(const uint32_t* __restrict__ bits, const uint32_t* __restrict__ hist,
                          const uint32_t* __restrict__ bsum, uint32_t* __restrict__ cursor,
                          uint32_t* __restrict__ pkey, uint32_t* __restrict__ pidx) {
  int i = blockIdx.x * blockDim.x + threadIdx.x;
  uint32_t key = bits[i];
  uint32_t bin = key >> 17;
  uint32_t pos = hist[bin] + bsum[bin >> 8] + atomicAdd(&cursor[bin], 1u);
  pkey[pos] = key; pidx[pos] = (uint32_t)i;
}

// rank within bucket (stable). limit==0: write full res; else write first
// `limit` positions of the final permutation AND gather x rows into krand.
__global__ void k_rank(const uint32_t* __restrict__ pkey, const uint32_t* __restrict__ pidx,
                       const uint32_t* __restrict__ hist, const uint32_t* __restrict__ bsum,
                       const uint32_t* __restrict__ cursor,
                       const uint32_t* __restrict__ srcvals, uint32_t* __restrict__ outv,
                       const float* __restrict__ x, float* __restrict__ krand,
                       int limit) {
  int s = blockIdx.x * blockDim.x + threadIdx.x;
  uint32_t myk = pkey[s], myi = pidx[s];
  uint32_t bin = myk >> 17;
  uint32_t start = hist[bin] + bsum[bin >> 8], cntb = cursor[bin];
  uint32_t r = 0;
  for (uint32_t t = 0; t < cntb; ++t) {
    uint32_t ok = pkey[start + t], oi = pidx[start + t];
    r += (ok < myk || (ok == myk && oi < myi)) ? 1u : 0u;
  }
  uint32_t pos = start + r;
  if (limit == 0) {
    outv[pos] = myi;   // res1[i] = original index at round-1 sorted position i
  } else if (pos < (uint32_t)limit) {
    uint32_t orig = srcvals[myi];      // final perm value
    const float4* xs = (const float4*)(x + (size_t)orig * DIM);
    float4* kd = (float4*)(krand + (size_t)pos * DIM);
    #pragma unroll
    for (int q = 0; q < 16; ++q) kd[q] = xs[q];
  }
}

// ======================= EMA update + finale =======================

__global__ __launch_bounds__(256) void k_elem_kernel(
    const double* __restrict__ ks64, const int* __restrict__ kcnt,
    const float* __restrict__ k_sum_in, const float* __restrict__ k_elem_in,
    const float* __restrict__ k_in, const float* __restrict__ krand,
    float* __restrict__ out, double* __restrict__ dbl) {
  __shared__ float lds[8];
  const float OMF = (float)(1.0 - 0.99);
  int e = blockIdx.x * blockDim.x + threadIdx.x;
  int b = e >> 6;
  float part = (float)ks64[e];
  float nks = 0.99f * k_sum_in[e] + OMF * part;
  out[O_NKS + e] = nks;
  float cnt = (float)kcnt[b];
  float ke = 0.99f * k_elem_in[b] + OMF * cnt;
  float nk = (ke >= 1.f) ? (nks / ke) : krand[e];
  out[O_NK + e] = nk;
  float dd = nk - k_in[e];
  float bsum = block_reduce_sum(dd * dd, lds);
  if (threadIdx.x == 0) atomicAdd(&dbl[4], (double)bsum);
}

__global__ __launch_bounds__(1024) void k_finale(
    const int* __restrict__ kcnt, const float* __restrict__ k_elem_in,
    float* __restrict__ out, const double* __restrict__ dbl) {
  __shared__ float ent_l[1024];
  __shared__ int u1_l[1024], u2_l[1024];
  const float OMF = (float)(1.0 - 0.99);
  int tid = threadIdx.x;
  float ent = 0.f; int used = 0, usage = 0;
  #pragma unroll
  for (int t = 0; t < 2; ++t) {
    int b = tid + t * 1024;
    float cnt = (float)kcnt[b];
    float ke = 0.99f * k_elem_in[b] + OMF * cnt;
    out[O_NKE + b] = ke;
    float p = cnt * (1.f / 131072.f);
    ent -= p * logf(p + 1e-8f);
    used += (cnt >= 1.f) ? 1 : 0;
    usage += (ke >= 1.f) ? 1 : 0;
  }
  ent_l[tid] = ent; u1_l[tid] = used; u2_l[tid] = usage;
  __syncthreads();
  for (int off = 512; off > 0; off >>= 1) {
    if (tid < off) {
      ent_l[tid] += ent_l[tid + off];
      u1_l[tid] += u1_l[tid + off];
      u2_l[tid] += u2_l[tid + off];
    }
    __syncthreads();
  }
  if (tid == 0) {
    double M = (double)M_ELEMS;
    double sumS = dbl[0], sumQ = dbl[1];
    double var = (sumQ - sumS * sumS / M) / M;
    out[O_PRE] = (float)sqrt(var > 0.0 ? var : 0.0);
    out[O_FIT] = (float)(dbl[2] / (double)N_ROWS);
    out[O_CL]  = (float)(dbl[2] / M);
    out[O_DK]  = (float)sqrt(dbl[4] / (double)(KB * DIM));
    out[O_ENT] = ent_l[0];
    out[O_USED] = (float)u1_l[0];
    out[O_UTOT] = (float)u2_l[0];
  }
}

// ======================= launch =======================

extern "C" void kernel_launch(void* const* d_in, const int* in_sizes, int n_in,
                              void* d_out, int out_size, void* d_ws, size_t ws_size,
                              hipStream_t stream) {
  (void)in_sizes; (void)n_in; (void)out_size; (void)ws_size;
  const float* x      = (const float*)d_in[0];
  const float* k      = (const float*)d_in[1];
  const float* k_sum  = (const float*)d_in[2];
  const float* k_elem = (const float*)d_in[3];
  float* out = (float*)d_out;
  char* ws = (char*)d_ws;

  double*   dbl   = (double*)(ws + A_DBL);
  int*      cnt   = (int*)(ws + A_CNT);
  float*    kk2n  = (float*)(ws + A_KK2N);
  unsigned short* kst = (unsigned short*)(ws + A_KST);
  int*      xli   = (int*)(ws + A_XLI);
  int*      kcnt  = (int*)(ws + A_KCNT);
  uint32_t* bcur  = (uint32_t*)(ws + A_BCUR);
  float*    krand = (float*)(ws + A_KRAND);
  uint32_t* boffs = (uint32_t*)(ws + A_BOFF);
  uint32_t* flag  = (uint32_t*)(ws + A_FLAG);
  uint32_t* rowl  = (uint32_t*)(ws + A_ROWL);
  double*   ks64  = (double*)(ws + A_KS64);
  uint32_t* bits  = (uint32_t*)(ws + A_BITS);
  uint32_t* pkey  = (uint32_t*)(ws + A_PKEY);
  uint32_t* hist  = (uint32_t*)(ws + A_HIST);
  uint32_t* bsum  = (uint32_t*)(ws + A_BSUM);
  uint32_t* cur   = (uint32_t*)(ws + A_CUR);
  uint32_t* pidx  = (uint32_t*)(ws + A_PIDX);
  uint32_t* res1  = (uint32_t*)(ws + A_RES1);

  (void)hipMemsetAsync(ws + A_DBL, 0, 128, stream);        // dbl + cnt
  (void)hipMemsetAsync(ws + A_KCNT, 0, 16384, stream);     // kcnt + bcur
  (void)hipMemsetAsync(ws + A_KS64, 0, 1048576, stream);   // f64 accumulators

  k_prep<<<512, 256, 0, stream>>>(k, kst, kk2n);
  k_main<<<512, 512, 0, stream>>>(x, kst, kk2n, xli, flag, cnt, dbl);
  k_rescan<<<256, 256, 0, stream>>>(flag, cnt, x, k, xli);
  k_finish<<<512, 256, 0, stream>>>(x, k, xli, out, dbl);

  // segment sum via counting sort + equal-work chunked accumulation
  k_hist_rows<<<512, 256, 0, stream>>>(xli, kcnt);
  k_scan_bins<<<1, 1024, 0, stream>>>(kcnt, boffs);
  k_scatter_rows<<<512, 256, 0, stream>>>(xli, boffs, bcur, rowl);
  k_segsum<<<2048, 256, 0, stream>>>(rowl, xli, x, ks64);

  // jax.random.permutation(key(42), 131072): 2 stable sort rounds
  (void)hipMemsetAsync(ws + A_HIST, 0, 262656, stream);    // hist + bsum + cur
  k_bits_hist<<<256, 256, 0, stream>>>(0, bits, hist);
  k_scanA<<<128, 256, 0, stream>>>(hist, bsum);
  k_scanB<<<1, 128, 0, stream>>>(bsum);
  k_scatter<<<512, 256, 0, stream>>>(bits, hist, bsum, cur, pkey, pidx);
  k_rank<<<512, 256, 0, stream>>>(pkey, pidx, hist, bsum, cur, nullptr, res1,
                                  nullptr, nullptr, 0);
  (void)hipMemsetAsync(ws + A_HIST, 0, 262656, stream);
  k_bits_hist<<<256, 256, 0, stream>>>(1, bits, hist);
  k_scanA<<<128, 256, 0, stream>>>(hist, bsum);
  k_scanB<<<1, 128, 0, stream>>>(bsum);
  k_scatter<<<512, 256, 0, stream>>>(bits, hist, bsum, cur, pkey, pidx);
  k_rank<<<512, 256, 0, stream>>>(pkey, pidx, hist, bsum, cur, res1, nullptr,
                                  x, krand, 2048);

  k_elem_kernel<<<512, 256, 0, stream>>>(ks64, kcnt, k_sum, k_elem, k, krand, out, dbl);
  k_finale<<<1, 1024, 0, stream>>>(kcnt, k_elem, out, dbl);
}

// Round 13
// 385.281 us; speedup vs baseline: 1.4109x; 1.0187x over previous
//
#include <hip/hip_runtime.h>
#include <stdint.h>

#define N_ROWS 131072
#define DIM 64
#define KB 2048
#define M_ELEMS 8388608  // N_ROWS*DIM

// ---- output offsets (float32 elements, concatenated in return order) ----
#define O_XL   0
#define O_XD   131072
#define O_CL   8519680
#define O_FIT  8519681
#define O_PRE  8519682
#define O_ENT  8519683
#define O_USED 8519684
#define O_UTOT 8519685
#define O_DK   8519686
#define O_NK   8519687
#define O_NKS  8650759
#define O_NKE  8781831

// ---- workspace byte offsets (stay <= 5267616, proven in r1) ----
#define A_DBL   0         // doubles: [0]=sumS,[1]=sumQ,[2]=sum cl,[4]=dk acc
#define A_CNT   64        // rescan counter (int)
#define A_KK2N  128       // 2048 f32 : -0.5*|k|^2
#define A_KST   8320      // 524288 B: pre-swizzled kh|kl tile images (128 tiles x 4096 B)
#define A_XLI   532608    // 131072 i32
#define A_KCNT  1056896   // 2048 i32
#define A_BCUR  1065088   // 2048 u32 (adjacent to KCNT: one memset)
#define A_KRAND 1073280   // 131072 f32
#define A_BOFF  1597568   // 2048 u32
#define A_FLAG  1605760   // 131072 u32 (dead after k_rescan)
#define A_ROWL  2130048   // 131072 u32 (dead after k_segsum)
#define A_KS64  2654336   // 131072 f64 (1 MB, live until k_elem)
// RNG phase overlays FLAG/ROWL (temporally disjoint):
#define A_BITS  1605760   // 131072 u32 (overlays FLAG)
#define A_PKEY  2130048   // 131072 u32 (overlays ROWL)
#define A_HIST  3702912   // 32768 u32
#define A_BSUM  3833984   // 128 u32 (pad 512)
#define A_CUR   3834496   // 32768 u32   [HIST..CUR contiguous: one memset 262656]
#define A_PIDX  3965568   // 131072 u32
#define A_RES1  4489856   // 131072 u32
#define WS_END  5014144   // < 5267616 ok

typedef short bf16x8 __attribute__((ext_vector_type(8)));
typedef float f32x4 __attribute__((ext_vector_type(4)));

#define GLL16(G, L) __builtin_amdgcn_global_load_lds( \
    (const __attribute__((address_space(1))) void*)(G), \
    (__attribute__((address_space(3))) void*)(L), 16, 0, 0)
#define GLL4(G, L) __builtin_amdgcn_global_load_lds( \
    (const __attribute__((address_space(1))) void*)(G), \
    (__attribute__((address_space(3))) void*)(L), 4, 0, 0)

// ======================= helpers =======================

__device__ __forceinline__ float block_reduce_sum(float v, float* lds) {
  #pragma unroll
  for (int off = 32; off > 0; off >>= 1) v += __shfl_down(v, off, 64);
  int lane = threadIdx.x & 63, wid = threadIdx.x >> 6;
  if (lane == 0) lds[wid] = v;
  __syncthreads();
  float r = 0.f;
  if (threadIdx.x == 0) {
    int nw = blockDim.x >> 6;
    for (int i = 0; i < nw; ++i) r += lds[i];
  }
  __syncthreads();
  return r;  // valid on thread 0
}

__device__ __forceinline__ unsigned short f2bf_rne(float f) {
  uint32_t u = __float_as_uint(f);
  uint32_t r = u + 0x7FFFu + ((u >> 16) & 1u);
  return (unsigned short)(r >> 16);
}

#define TF_ROUND(r) do { x0 += x1; x1 = (x1 << (r)) | (x1 >> (32 - (r))); x1 ^= x0; } while (0)

__device__ __forceinline__ void threefry2x32(uint32_t k0, uint32_t k1,
                                             uint32_t c0, uint32_t c1,
                                             uint32_t& o0, uint32_t& o1) {
  uint32_t k2 = k0 ^ k1 ^ 0x1BD11BDAu;
  uint32_t x0 = c0 + k0, x1 = c1 + k1;
  TF_ROUND(13); TF_ROUND(15); TF_ROUND(26); TF_ROUND(6);
  x0 += k1; x1 += k2 + 1u;
  TF_ROUND(17); TF_ROUND(29); TF_ROUND(16); TF_ROUND(24);
  x0 += k2; x1 += k0 + 2u;
  TF_ROUND(13); TF_ROUND(15); TF_ROUND(26); TF_ROUND(6);
  x0 += k0; x1 += k1 + 3u;
  TF_ROUND(17); TF_ROUND(29); TF_ROUND(16); TF_ROUND(24);
  x0 += k1; x1 += k2 + 4u;
  TF_ROUND(13); TF_ROUND(15); TF_ROUND(26); TF_ROUND(6);
  x0 += k2; x1 += k0 + 5u;
  o0 = x0; o1 = x1;
}

// ======================= codebook prep =======================
// one wave per code row. Writes the PRE-SWIZZLED kh|kl tile image so that
// a linear global_load_lds produces bank-spread ds_read_b128 fragments:
// tile t (4096 B) = [kh 2048 B | kl 2048 B]; within each half, (code r, dim d)
// lives at byte r*128 + (((d>>3) ^ (r&7))<<4) + (d&7)*2.
__global__ __launch_bounds__(256) void k_prep(
    const float* __restrict__ k, unsigned short* __restrict__ kst,
    float* __restrict__ kk2n) {
  int w = (blockIdx.x * blockDim.x + threadIdx.x) >> 6;  // code j, 2048 waves
  int lane = threadIdx.x & 63;                           // dim d
  float v = k[(size_t)w * DIM + lane];
  unsigned short h = f2bf_rne(v);
  float hf = __uint_as_float((uint32_t)h << 16);
  unsigned short lo = f2bf_rne(v - hf);
  int t = w >> 4, r = w & 15;
  int c = lane >> 3, e = lane & 7;
  int slot = c ^ (r & 7);
  size_t u16i = (size_t)t * 2048 + r * 64 + slot * 8 + e;
  kst[u16i] = h;           // kh half
  kst[u16i + 1024] = lo;   // kl half (+2048 B)
  float q = v * v;
  #pragma unroll
  for (int off = 32; off > 0; off >>= 1) q += __shfl_down(q, off, 64);
  if (lane == 0) kk2n[w] = -0.5f * q;
}

// ======================= MFMA argmin (LDS-staged k, g=4) ====================
// 256 threads = 4 waves, g=4 (64 rows/wave, 256 rows/block), 512 blocks (2/CU).
// 64-code staging steps (16.6 KB x2, double-buffered), ONE barrier per step:
//   barrier -> issue stage(t+1) -> compute buf[t&1]
// so the prefetch drains at the NEXT barrier, hidden under ~96 MFMAs.
// Index tracked INLINE (proven round-11 semantics; round-12 deferred replay
// failed correctness).
__global__ __launch_bounds__(256) void k_main(
    const float* __restrict__ x, const unsigned short* __restrict__ kst,
    const float* __restrict__ kk2n,
    int* __restrict__ xli, uint32_t* __restrict__ flag, int* __restrict__ cnt,
    double* __restrict__ dbl) {
  __shared__ __align__(16) char smem[2][16640];   // 16384 frag + 256 kk each
  __shared__ float lds_red[4];
  int tid = threadIdx.x;
  int lane = tid & 63;
  int wid = tid >> 6;           // 0..3
  int lrow = lane & 15;
  int lk = lane >> 4;           // 0..3
  int r0 = (blockIdx.x * 4 + wid) * 64;   // 64 rows per wave

  // load + decompose x fragments: 4 row-groups x 2 K-halves
  bf16x8 xh[4][2], xl[4][2];
  float s_acc = 0.f, q_acc = 0.f;
  #pragma unroll
  for (int g = 0; g < 4; ++g) {
    #pragma unroll
    for (int kt = 0; kt < 2; ++kt) {
      const float* xp = x + (size_t)(r0 + g * 16 + lrow) * DIM + kt * 32 + lk * 8;
      float4 v0 = *(const float4*)xp;
      float4 v1 = *(const float4*)(xp + 4);
      float vv[8] = {v0.x, v0.y, v0.z, v0.w, v1.x, v1.y, v1.z, v1.w};
      #pragma unroll
      for (int i = 0; i < 8; ++i) {
        float v = vv[i];
        s_acc += v;
        q_acc = fmaf(v, v, q_acc);
        unsigned short h = f2bf_rne(v);
        float hf = __uint_as_float((uint32_t)h << 16);
        xh[g][kt][i] = (short)h;
        xl[g][kt][i] = (short)f2bf_rne(v - hf);
      }
    }
  }
  // prenorm partial sums (x loaded exactly once grid-wide)
  float bs = block_reduce_sum(s_acc, lds_red);
  float bq = block_reduce_sum(q_acc, lds_red);
  if (tid == 0) {
    atomicAdd(&dbl[0], (double)bs);
    atomicAdd(&dbl[1], (double)bq);
  }

  // loop-invariant swizzled fragment byte offsets (within a 2048-B half)
  int offH0 = lrow * 128 + (((lk    ) ^ (lrow & 7)) << 4);
  int offH1 = lrow * 128 + (((lk + 4) ^ (lrow & 7)) << 4);

  const char* kst_b = (const char*)kst;
  const char* kk_b  = (const char*)kk2n;

  // prologue: stage step 0 into buffer 0 (4 x GLL16/thread + kk by wave 0)
  {
    char* ldst = &smem[0][0];
    #pragma unroll
    for (int c = 0; c < 4; ++c)
      GLL16(kst_b + c * 4096 + tid * 16, ldst + c * 4096 + tid * 16);
    if (wid == 0) GLL4(kk_b + lane * 4, ldst + 16384 + lane * 4);
  }

  float b1[4], b2[4];
  uint32_t j1[4];
  #pragma unroll
  for (int g = 0; g < 4; ++g) {
    b1[g] = -3.402823466e38f; b2[g] = -3.402823466e38f; j1[g] = 0;
  }

  for (int t = 0; t < 32; ++t) {
    __syncthreads();   // stage(t) resident; all waves done reading buf[(t+1)&1]
    if (t + 1 < 32) {
      const char* gsrc = kst_b + (size_t)(t + 1) * 16384;
      char* ldst = &smem[(t + 1) & 1][0];
      #pragma unroll
      for (int c = 0; c < 4; ++c)
        GLL16(gsrc + c * 4096 + tid * 16, ldst + c * 4096 + tid * 16);
      if (wid == 0) GLL4(kk_b + (size_t)(t + 1) * 256 + lane * 4, ldst + 16384 + lane * 4);
    }
    const char* B = &smem[t & 1][0];
    #pragma unroll
    for (int s = 0; s < 4; ++s) {
      bf16x8 ah0 = *(const bf16x8*)(B + s * 4096 + offH0);
      bf16x8 ah1 = *(const bf16x8*)(B + s * 4096 + offH1);
      bf16x8 al0 = *(const bf16x8*)(B + s * 4096 + 2048 + offH0);
      bf16x8 al1 = *(const bf16x8*)(B + s * 4096 + 2048 + offH1);
      f32x4 kkv  = *(const f32x4*)(B + 16384 + s * 64 + lk * 16);
      uint32_t jb = (uint32_t)(t * 64 + s * 16 + lk * 4);
      #pragma unroll
      for (int g = 0; g < 4; ++g) {
        f32x4 acc = __builtin_amdgcn_mfma_f32_16x16x32_bf16(ah0, xh[g][0], kkv, 0, 0, 0);
        acc = __builtin_amdgcn_mfma_f32_16x16x32_bf16(ah1, xh[g][1], acc, 0, 0, 0);
        acc = __builtin_amdgcn_mfma_f32_16x16x32_bf16(al0, xh[g][0], acc, 0, 0, 0);
        acc = __builtin_amdgcn_mfma_f32_16x16x32_bf16(al1, xh[g][1], acc, 0, 0, 0);
        acc = __builtin_amdgcn_mfma_f32_16x16x32_bf16(ah0, xl[g][0], acc, 0, 0, 0);
        acc = __builtin_amdgcn_mfma_f32_16x16x32_bf16(ah1, xl[g][1], acc, 0, 0, 0);
        #pragma unroll
        for (int reg = 0; reg < 4; ++reg) {
          float v = acc[reg];
          bool gt = v > b1[g];
          float mn = fminf(v, b1[g]);
          b2[g] = fmaxf(b2[g], mn);
          b1[g] = gt ? v : b1[g];
          j1[g] = gt ? (jb + (uint32_t)reg) : j1[g];
        }
      }
    }
  }

  // merge the 4 lanes (lane^16, lane^32) sharing one x-row; epilogue
  #pragma unroll
  for (int g = 0; g < 4; ++g) {
    #pragma unroll
    for (int s = 16; s <= 32; s <<= 1) {
      float ob1 = __shfl_xor(b1[g], s, 64);
      float ob2 = __shfl_xor(b2[g], s, 64);
      uint32_t oj1 = __shfl_xor(j1[g], s, 64);
      bool gt = ob1 > b1[g];
      float mn = fminf(b1[g], ob1);
      b2[g] = fmaxf(fmaxf(b2[g], ob2), mn);
      b1[g] = fmaxf(b1[g], ob1);
      j1[g] = gt ? oj1 : j1[g];
    }
    if (lk == 0) {
      int row = r0 + g * 16 + lrow;
      xli[row] = (int)j1[g];
      if (b1[g] - b2[g] < 0.01f) {  // score gap = dist gap / 2
        int i = atomicAdd(cnt, 1);
        flag[i] = (uint32_t)row;
      }
    }
  }
}

// exact fp64 full rescan for near-tie rows; one wave per row
__global__ __launch_bounds__(256) void k_rescan(
    const uint32_t* __restrict__ flag, const int* __restrict__ cnt,
    const float* __restrict__ x, const float* __restrict__ k,
    int* __restrict__ xli) {
  __shared__ float xs[4][64];
  int lane = threadIdx.x & 63;
  int wid = threadIdx.x >> 6;
  int gw = (blockIdx.x * blockDim.x + threadIdx.x) >> 6;
  int n = *cnt;
  for (int fi = gw; fi < n; fi += 1024) {
    int row = flag[fi];
    xs[wid][lane] = x[(size_t)row * DIM + lane];  // wave-synchronous LDS
    double bd = 1e300;
    int bj = 0;
    for (int j = lane; j < KB; j += 64) {
      const float* kr = k + (size_t)j * DIM;
      double e = 0.0;
      #pragma unroll
      for (int d = 0; d < DIM; ++d) {
        double diff = (double)xs[wid][d] - (double)kr[d];
        e = fma(diff, diff, e);
      }
      if (e < bd) { bd = e; bj = j; }
    }
    #pragma unroll
    for (int off = 32; off > 0; off >>= 1) {
      double od = __shfl_down(bd, off, 64);
      int oj = __shfl_down(bj, off, 64);
      if (od < bd || (od == bd && oj < bj)) { bd = od; bj = oj; }
    }
    if (lane == 0) xli[row] = bj;
  }
}

// exact kcnt histogram, built AFTER rescan corrections
__global__ void k_hist_rows(const int* __restrict__ xli, int* __restrict__ kcnt) {
  int i = blockIdx.x * blockDim.x + threadIdx.x;
  atomicAdd(&kcnt[xli[i]], 1);
}

__global__ __launch_bounds__(256) void k_finish(
    const float* __restrict__ x, const float* __restrict__ k,
    const int* __restrict__ xli, float* __restrict__ out,
    double* __restrict__ dbl) {
  __shared__ float lds[8];
  int row = blockIdx.x * blockDim.x + threadIdx.x;
  int j = xli[row];
  out[O_XL + row] = (float)j;
  const float4* xp = (const float4*)(x + (size_t)row * DIM);
  const float4* kp = (const float4*)(k + (size_t)j * DIM);
  float4* xd = (float4*)(out + O_XD + (size_t)row * DIM);
  float a = 0.f, b = 0.f, c = 0.f, d = 0.f;
  #pragma unroll
  for (int q = 0; q < 16; ++q) {
    float4 kv = kp[q];
    float4 xv = xp[q];
    xd[q] = kv;
    float dx = kv.x - xv.x, dy = kv.y - xv.y;
    float dz = kv.z - xv.z, dw = kv.w - xv.w;
    a = fmaf(dx, dx, a); b = fmaf(dy, dy, b);
    c = fmaf(dz, dz, c); d = fmaf(dw, dw, d);
  }
  float cl = (a + b) + (c + d);    // == min dist (fit & commit share this)
  float bc = block_reduce_sum(cl, lds);
  if (threadIdx.x == 0) atomicAdd(&dbl[2], (double)bc);
}

// ======================= segment sum via counting sort =======================

__global__ __launch_bounds__(1024) void k_scan_bins(const int* __restrict__ kcnt,
                                                    uint32_t* __restrict__ boffs) {
  __shared__ uint32_t part[1024];
  int tid = threadIdx.x;
  uint32_t c0 = (uint32_t)kcnt[2 * tid];
  uint32_t c1 = (uint32_t)kcnt[2 * tid + 1];
  part[tid] = c0 + c1;
  __syncthreads();
  for (int off = 1; off < 1024; off <<= 1) {
    uint32_t v = (tid >= off) ? part[tid - off] : 0u;
    __syncthreads();
    part[tid] += v;
    __syncthreads();
  }
  uint32_t run = (tid > 0) ? part[tid - 1] : 0u;
  boffs[2 * tid] = run;
  boffs[2 * tid + 1] = run + c0;
}

__global__ void k_scatter_rows(const int* __restrict__ xli, const uint32_t* __restrict__ boffs,
                               uint32_t* __restrict__ bcur, uint32_t* __restrict__ rowlist) {
  int i = blockIdx.x * blockDim.x + threadIdx.x;
  int b = xli[i];
  uint32_t pos = boffs[b] + atomicAdd(&bcur[b], 1u);
  rowlist[pos] = (uint32_t)i;
}

// equal-work segment sum: one wave per 16 rowlist positions; lane = dim column.
__global__ __launch_bounds__(256) void k_segsum(
    const uint32_t* __restrict__ rowlist, const int* __restrict__ xli,
    const float* __restrict__ x, double* __restrict__ ks64) {
  int gw = (blockIdx.x * blockDim.x + threadIdx.x) >> 6;  // 8192 waves
  int lane = threadIdx.x & 63;
  uint32_t p0 = (uint32_t)gw * 16;
  double acc = 0.0;
  int cur = -1;
  #pragma unroll 4
  for (int i = 0; i < 16; ++i) {
    uint32_t row = rowlist[p0 + i];
    int bin = xli[row];
    if (bin != cur) {
      if (cur >= 0) atomicAdd(&ks64[(size_t)cur * DIM + lane], acc);
      acc = 0.0; cur = bin;
    }
    acc += (double)x[(size_t)row * DIM + lane];
  }
  if (cur >= 0) atomicAdd(&ks64[(size_t)cur * DIM + lane], acc);
}

// ---- JAX threefry permutation replication (15-bit bucket sort x2) ----

__global__ void k_bits_hist(int which, uint32_t* __restrict__ bits,
                            uint32_t* __restrict__ hist) {
  uint32_t a0, a1, b0, b1;
  threefry2x32(0u, 42u, 0u, 2u, a0, b0);
  threefry2x32(0u, 42u, 1u, 3u, a1, b1);
  uint32_t k0, k1;
  if (which == 0) { k0 = b0; k1 = b1; }
  else {
    uint32_t c0, c1, d0, d1;
    threefry2x32(a0, a1, 0u, 2u, c0, d0);
    threefry2x32(a0, a1, 1u, 3u, c1, d1);
    k0 = d0; k1 = d1;
  }
  int i = blockIdx.x * blockDim.x + threadIdx.x;  // 65536 threads
  uint32_t y0, y1;
  threefry2x32(k0, k1, (uint32_t)i, (uint32_t)(i + 65536), y0, y1);
  bits[i] = y0;
  bits[i + 65536] = y1;
  atomicAdd(&hist[y0 >> 17], 1u);
  atomicAdd(&hist[y1 >> 17], 1u);
}

// local exclusive scan of 256 bins per block; in-place; block total -> bsum
__global__ __launch_bounds__(256) void k_scanA(uint32_t* __restrict__ hist,
                                               uint32_t* __restrict__ bsum) {
  __shared__ uint32_t sh[256];
  int tid = threadIdx.x;
  int bin = blockIdx.x * 256 + tid;
  uint32_t v = hist[bin];
  sh[tid] = v;
  __syncthreads();
  for (int off = 1; off < 256; off <<= 1) {
    uint32_t t = (tid >= off) ? sh[tid - off] : 0u;
    __syncthreads();
    sh[tid] += t;
    __syncthreads();
  }
  hist[bin] = sh[tid] - v;                 // exclusive local prefix
  if (tid == 255) bsum[blockIdx.x] = sh[tid];
}

__global__ void k_scanB(uint32_t* __restrict__ bsum) {  // 1 block, 128 threads
  __shared__ uint32_t sh[128];
  int tid = threadIdx.x;
  uint32_t v = bsum[tid];
  sh[tid] = v;
  __syncthreads();
  for (int off = 1; off < 128; off <<= 1) {
    uint32_t t = (tid >= off) ? sh[tid - off] : 0u;
    __syncthreads();
    sh[tid] += t;
    __syncthreads();
  }
  bsum[tid] = sh[tid] - v;  // exclusive
}

__global__ void k_scatter(const uint32_t* __restrict__ bits, const uint32_t* __restrict__ hist,
                          const uint32_t* __restrict__ bsum, uint32_t* __restrict__ cursor,
                          uint32_t* __restrict__ pkey, uint32_t* __restrict__ pidx) {
  int i = blockIdx.x * blockDim.x + threadIdx.x;
  uint32_t key = bits[i];
  uint32_t bin = key >> 17;
  uint32_t pos = hist[bin] + bsum[bin >> 8] + atomicAdd(&cursor[bin], 1u);
  pkey[pos] = key; pidx[pos] = (uint32_t)i;
}

// rank within bucket (stable). limit==0: write full res; else write first
// `limit` positions of the final permutation AND gather x rows into krand.
__global__ void k_rank(const uint32_t* __restrict__ pkey, const uint32_t* __restrict__ pidx,
                       const uint32_t* __restrict__ hist, const uint32_t* __restrict__ bsum,
                       const uint32_t* __restrict__ cursor,
                       const uint32_t* __restrict__ srcvals, uint32_t* __restrict__ outv,
                       const float* __restrict__ x, float* __restrict__ krand,
                       int limit) {
  int s = blockIdx.x * blockDim.x + threadIdx.x;
  uint32_t myk = pkey[s], myi = pidx[s];
  uint32_t bin = myk >> 17;
  uint32_t start = hist[bin] + bsum[bin >> 8], cntb = cursor[bin];
  uint32_t r = 0;
  for (uint32_t t = 0; t < cntb; ++t) {
    uint32_t ok = pkey[start + t], oi = pidx[start + t];
    r += (ok < myk || (ok == myk && oi < myi)) ? 1u : 0u;
  }
  uint32_t pos = start + r;
  if (limit == 0) {
    outv[pos] = myi;   // res1[i] = original index at round-1 sorted position i
  } else if (pos < (uint32_t)limit) {
    uint32_t orig = srcvals[myi];      // final perm value
    const float4* xs = (const float4*)(x + (size_t)orig * DIM);
    float4* kd = (float4*)(krand + (size_t)pos * DIM);
    #pragma unroll
    for (int q = 0; q < 16; ++q) kd[q] = xs[q];
  }
}

// ======================= EMA update + finale =======================

__global__ __launch_bounds__(256) void k_elem_kernel(
    const double* __restrict__ ks64, const int* __restrict__ kcnt,
    const float* __restrict__ k_sum_in, const float* __restrict__ k_elem_in,
    const float* __restrict__ k_in, const float* __restrict__ krand,
    float* __restrict__ out, double* __restrict__ dbl) {
  __shared__ float lds[8];
  const float OMF = (float)(1.0 - 0.99);
  int e = blockIdx.x * blockDim.x + threadIdx.x;
  int b = e >> 6;
  float part = (float)ks64[e];
  float nks = 0.99f * k_sum_in[e] + OMF * part;
  out[O_NKS + e] = nks;
  float cnt = (float)kcnt[b];
  float ke = 0.99f * k_elem_in[b] + OMF * cnt;
  float nk = (ke >= 1.f) ? (nks / ke) : krand[e];
  out[O_NK + e] = nk;
  float dd = nk - k_in[e];
  float bsum = block_reduce_sum(dd * dd, lds);
  if (threadIdx.x == 0) atomicAdd(&dbl[4], (double)bsum);
}

__global__ __launch_bounds__(1024) void k_finale(
    const int* __restrict__ kcnt, const float* __restrict__ k_elem_in,
    float* __restrict__ out, const double* __restrict__ dbl) {
  __shared__ float ent_l[1024];
  __shared__ int u1_l[1024], u2_l[1024];
  const float OMF = (float)(1.0 - 0.99);
  int tid = threadIdx.x;
  float ent = 0.f; int used = 0, usage = 0;
  #pragma unroll
  for (int t = 0; t < 2; ++t) {
    int b = tid + t * 1024;
    float cnt = (float)kcnt[b];
    float ke = 0.99f * k_elem_in[b] + OMF * cnt;
    out[O_NKE + b] = ke;
    float p = cnt * (1.f / 131072.f);
    ent -= p * logf(p + 1e-8f);
    used += (cnt >= 1.f) ? 1 : 0;
    usage += (ke >= 1.f) ? 1 : 0;
  }
  ent_l[tid] = ent; u1_l[tid] = used; u2_l[tid] = usage;
  __syncthreads();
  for (int off = 512; off > 0; off >>= 1) {
    if (tid < off) {
      ent_l[tid] += ent_l[tid + off];
      u1_l[tid] += u1_l[tid + off];
      u2_l[tid] += u2_l[tid + off];
    }
    __syncthreads();
  }
  if (tid == 0) {
    double M = (double)M_ELEMS;
    double sumS = dbl[0], sumQ = dbl[1];
    double var = (sumQ - sumS * sumS / M) / M;
    out[O_PRE] = (float)sqrt(var > 0.0 ? var : 0.0);
    out[O_FIT] = (float)(dbl[2] / (double)N_ROWS);
    out[O_CL]  = (float)(dbl[2] / M);
    out[O_DK]  = (float)sqrt(dbl[4] / (double)(KB * DIM));
    out[O_ENT] = ent_l[0];
    out[O_USED] = (float)u1_l[0];
    out[O_UTOT] = (float)u2_l[0];
  }
}

// ======================= launch =======================

extern "C" void kernel_launch(void* const* d_in, const int* in_sizes, int n_in,
                              void* d_out, int out_size, void* d_ws, size_t ws_size,
                              hipStream_t stream) {
  (void)in_sizes; (void)n_in; (void)out_size; (void)ws_size;
  const float* x      = (const float*)d_in[0];
  const float* k      = (const float*)d_in[1];
  const float* k_sum  = (const float*)d_in[2];
  const float* k_elem = (const float*)d_in[3];
  float* out = (float*)d_out;
  char* ws = (char*)d_ws;

  double*   dbl   = (double*)(ws + A_DBL);
  int*      cnt   = (int*)(ws + A_CNT);
  float*    kk2n  = (float*)(ws + A_KK2N);
  unsigned short* kst = (unsigned short*)(ws + A_KST);
  int*      xli   = (int*)(ws + A_XLI);
  int*      kcnt  = (int*)(ws + A_KCNT);
  uint32_t* bcur  = (uint32_t*)(ws + A_BCUR);
  float*    krand = (float*)(ws + A_KRAND);
  uint32_t* boffs = (uint32_t*)(ws + A_BOFF);
  uint32_t* flag  = (uint32_t*)(ws + A_FLAG);
  uint32_t* rowl  = (uint32_t*)(ws + A_ROWL);
  double*   ks64  = (double*)(ws + A_KS64);
  uint32_t* bits  = (uint32_t*)(ws + A_BITS);
  uint32_t* pkey  = (uint32_t*)(ws + A_PKEY);
  uint32_t* hist  = (uint32_t*)(ws + A_HIST);
  uint32_t* bsum  = (uint32_t*)(ws + A_BSUM);
  uint32_t* cur   = (uint32_t*)(ws + A_CUR);
  uint32_t* pidx  = (uint32_t*)(ws + A_PIDX);
  uint32_t* res1  = (uint32_t*)(ws + A_RES1);

  (void)hipMemsetAsync(ws + A_DBL, 0, 128, stream);        // dbl + cnt
  (void)hipMemsetAsync(ws + A_KCNT, 0, 16384, stream);     // kcnt + bcur
  (void)hipMemsetAsync(ws + A_KS64, 0, 1048576, stream);   // f64 accumulators

  k_prep<<<512, 256, 0, stream>>>(k, kst, kk2n);
  k_main<<<512, 256, 0, stream>>>(x, kst, kk2n, xli, flag, cnt, dbl);
  k_rescan<<<256, 256, 0, stream>>>(flag, cnt, x, k, xli);
  k_finish<<<512, 256, 0, stream>>>(x, k, xli, out, dbl);

  // segment sum via counting sort + equal-work chunked accumulation
  k_hist_rows<<<512, 256, 0, stream>>>(xli, kcnt);
  k_scan_bins<<<1, 1024, 0, stream>>>(kcnt, boffs);
  k_scatter_rows<<<512, 256, 0, stream>>>(xli, boffs, bcur, rowl);
  k_segsum<<<2048, 256, 0, stream>>>(rowl, xli, x, ks64);

  // jax.random.permutation(key(42), 131072): 2 stable sort rounds
  (void)hipMemsetAsync(ws + A_HIST, 0, 262656, stream);    // hist + bsum + cur
  k_bits_hist<<<256, 256, 0, stream>>>(0, bits, hist);
  k_scanA<<<128, 256, 0, stream>>>(hist, bsum);
  k_scanB<<<1, 128, 0, stream>>>(bsum);
  k_scatter<<<512, 256, 0, stream>>>(bits, hist, bsum, cur, pkey, pidx);
  k_rank<<<512, 256, 0, stream>>>(pkey, pidx, hist, bsum, cur, nullptr, res1,
                                  nullptr, nullptr, 0);
  (void)hipMemsetAsync(ws + A_HIST, 0, 262656, stream);
  k_bits_hist<<<256, 256, 0, stream>>>(1, bits, hist);
  k_scanA<<<128, 256, 0, stream>>>(hist, bsum);
  k_scanB<<<1, 128, 0, stream>>>(bsum);
  k_scatter<<<512, 256, 0, stream>>>(bits, hist, bsum, cur, pkey, pidx);
  k_rank<<<512, 256, 0, stream>>>(pkey, pidx, hist, bsum, cur, res1, nullptr,
                                  x, krand, 2048);

  k_elem_kernel<<<512, 256, 0, stream>>>(ks64, kcnt, k_sum, k_elem, k, krand, out, dbl);
  k_finale<<<1, 1024, 0, stream>>>(kcnt, k_elem, out, dbl);
}

// Round 14
// 374.571 us; speedup vs baseline: 1.4512x; 1.0286x over previous
//
#include <hip/hip_runtime.h>
#include <stdint.h>

#define N_ROWS 131072
#define DIM 64
#define KB 2048
#define M_ELEMS 8388608  // N_ROWS*DIM

// ---- output offsets (float32 elements, concatenated in return order) ----
#define O_XL   0
#define O_XD   131072
#define O_CL   8519680
#define O_FIT  8519681
#define O_PRE  8519682
#define O_ENT  8519683
#define O_USED 8519684
#define O_UTOT 8519685
#define O_DK   8519686
#define O_NK   8519687
#define O_NKS  8650759
#define O_NKE  8781831

// ---- workspace byte offsets (stay <= 5267616, proven in r1) ----
#define A_DBL   0         // doubles: [0]=sumS,[1]=sumQ,[2]=sum cl,[4]=dk acc
#define A_CNT   64        // rescan counter (int)
#define A_KK2N  128       // 2048 f32 : -0.5*|k|^2
#define A_KST   8320      // 524288 B: pre-swizzled kh|kl tile images (128 tiles x 4096 B)
#define A_XLI   532608    // 131072 i32
#define A_KCNT  1056896   // 2048 i32
#define A_BCUR  1065088   // 2048 u32 (adjacent to KCNT: one memset)
#define A_KRAND 1073280   // 131072 f32
#define A_BOFF  1597568   // 2048 u32
#define A_FLAG  1605760   // 131072 u32 (dead after k_rescan)
#define A_ROWL  2130048   // 131072 u32 (dead after k_segsum)
#define A_KS64  2654336   // 131072 f64 (1 MB, live until k_elem)
// RNG phase overlays FLAG/ROWL (temporally disjoint):
#define A_BITS  1605760   // 131072 u32 (overlays FLAG)
#define A_PKEY  2130048   // 131072 u32 (overlays ROWL)
#define A_HIST  3702912   // 32768 u32
#define A_BSUM  3833984   // 128 u32 (pad 512)
#define A_CUR   3834496   // 32768 u32   [HIST..CUR contiguous: one memset 262656]
#define A_PIDX  3965568   // 131072 u32
#define A_RES1  4489856   // 131072 u32
#define WS_END  5014144   // < 5267616 ok

typedef short bf16x8 __attribute__((ext_vector_type(8)));
typedef float f32x4 __attribute__((ext_vector_type(4)));

#define GLL16(G, L) __builtin_amdgcn_global_load_lds( \
    (const __attribute__((address_space(1))) void*)(G), \
    (__attribute__((address_space(3))) void*)(L), 16, 0, 0)
#define GLL4(G, L) __builtin_amdgcn_global_load_lds( \
    (const __attribute__((address_space(1))) void*)(G), \
    (__attribute__((address_space(3))) void*)(L), 4, 0, 0)

// ======================= helpers =======================

__device__ __forceinline__ float block_reduce_sum(float v, float* lds) {
  #pragma unroll
  for (int off = 32; off > 0; off >>= 1) v += __shfl_down(v, off, 64);
  int lane = threadIdx.x & 63, wid = threadIdx.x >> 6;
  if (lane == 0) lds[wid] = v;
  __syncthreads();
  float r = 0.f;
  if (threadIdx.x == 0) {
    int nw = blockDim.x >> 6;
    for (int i = 0; i < nw; ++i) r += lds[i];
  }
  __syncthreads();
  return r;  // valid on thread 0
}

__device__ __forceinline__ unsigned short f2bf_rne(float f) {
  uint32_t u = __float_as_uint(f);
  uint32_t r = u + 0x7FFFu + ((u >> 16) & 1u);
  return (unsigned short)(r >> 16);
}

#define TF_ROUND(r) do { x0 += x1; x1 = (x1 << (r)) | (x1 >> (32 - (r))); x1 ^= x0; } while (0)

__device__ __forceinline__ void threefry2x32(uint32_t k0, uint32_t k1,
                                             uint32_t c0, uint32_t c1,
                                             uint32_t& o0, uint32_t& o1) {
  uint32_t k2 = k0 ^ k1 ^ 0x1BD11BDAu;
  uint32_t x0 = c0 + k0, x1 = c1 + k1;
  TF_ROUND(13); TF_ROUND(15); TF_ROUND(26); TF_ROUND(6);
  x0 += k1; x1 += k2 + 1u;
  TF_ROUND(17); TF_ROUND(29); TF_ROUND(16); TF_ROUND(24);
  x0 += k2; x1 += k0 + 2u;
  TF_ROUND(13); TF_ROUND(15); TF_ROUND(26); TF_ROUND(6);
  x0 += k0; x1 += k1 + 3u;
  TF_ROUND(17); TF_ROUND(29); TF_ROUND(16); TF_ROUND(24);
  x0 += k1; x1 += k2 + 4u;
  TF_ROUND(13); TF_ROUND(15); TF_ROUND(26); TF_ROUND(6);
  x0 += k2; x1 += k0 + 5u;
  o0 = x0; o1 = x1;
}

// ======================= codebook prep =======================
// one wave per code row. Writes the PRE-SWIZZLED kh|kl tile image so that
// a linear global_load_lds produces bank-spread ds_read_b128 fragments:
// tile t (4096 B) = [kh 2048 B | kl 2048 B]; within each half, (code r, dim d)
// lives at byte r*128 + (((d>>3) ^ (r&7))<<4) + (d&7)*2.
__global__ __launch_bounds__(256) void k_prep(
    const float* __restrict__ k, unsigned short* __restrict__ kst,
    float* __restrict__ kk2n) {
  int w = (blockIdx.x * blockDim.x + threadIdx.x) >> 6;  // code j, 2048 waves
  int lane = threadIdx.x & 63;                           // dim d
  float v = k[(size_t)w * DIM + lane];
  unsigned short h = f2bf_rne(v);
  float hf = __uint_as_float((uint32_t)h << 16);
  unsigned short lo = f2bf_rne(v - hf);
  int t = w >> 4, r = w & 15;
  int c = lane >> 3, e = lane & 7;
  int slot = c ^ (r & 7);
  size_t u16i = (size_t)t * 2048 + r * 64 + slot * 8 + e;
  kst[u16i] = h;           // kh half
  kst[u16i + 1024] = lo;   // kl half (+2048 B)
  float q = v * v;
  #pragma unroll
  for (int off = 32; off > 0; off >>= 1) q += __shfl_down(q, off, 64);
  if (lane == 0) kk2n[w] = -0.5f * q;
}

// ======================= MFMA argmin (LDS-staged k, g=2, 4 blk/CU) ==========
// 256 threads = 4 waves, g=2 (32 rows/wave, 128 rows/block), 1024 blocks
// (4/CU -> 4 waves/SIMD). 64-code staging steps (16.6 KB x2, double-buffered),
// ONE barrier per step: barrier -> issue stage(t+1) -> compute buf[t&1].
// Fused epilogue: xli + out[O_XL] + x_d gather-write + fit/commit cl sum
// (cl = xx - 2*score), prenorm sums, tie-flag.
__global__ __launch_bounds__(256) void k_main(
    const float* __restrict__ x, const float* __restrict__ korig,
    const unsigned short* __restrict__ kst, const float* __restrict__ kk2n,
    int* __restrict__ xli, uint32_t* __restrict__ flag, int* __restrict__ cnt,
    float* __restrict__ out, double* __restrict__ dbl) {
  __shared__ __align__(16) char smem[2][16640];   // 16384 frag + 256 kk each
  __shared__ float lds_red[4];
  int tid = threadIdx.x;
  int lane = tid & 63;
  int wid = tid >> 6;           // 0..3
  int lrow = lane & 15;
  int lk = lane >> 4;           // 0..3
  int r0 = (blockIdx.x * 4 + wid) * 32;   // 32 rows per wave

  // load + decompose x fragments: 2 row-groups x 2 K-halves
  bf16x8 xh[2][2], xl[2][2];
  float qrow[2] = {0.f, 0.f};
  float s_acc = 0.f;
  #pragma unroll
  for (int g = 0; g < 2; ++g) {
    #pragma unroll
    for (int kt = 0; kt < 2; ++kt) {
      const float* xp = x + (size_t)(r0 + g * 16 + lrow) * DIM + kt * 32 + lk * 8;
      float4 v0 = *(const float4*)xp;
      float4 v1 = *(const float4*)(xp + 4);
      float vv[8] = {v0.x, v0.y, v0.z, v0.w, v1.x, v1.y, v1.z, v1.w};
      #pragma unroll
      for (int i = 0; i < 8; ++i) {
        float v = vv[i];
        s_acc += v;
        qrow[g] = fmaf(v, v, qrow[g]);
        unsigned short h = f2bf_rne(v);
        float hf = __uint_as_float((uint32_t)h << 16);
        xh[g][kt][i] = (short)h;
        xl[g][kt][i] = (short)f2bf_rne(v - hf);
      }
    }
  }
  // prenorm partial sums (x loaded exactly once grid-wide)
  float bs = block_reduce_sum(s_acc, lds_red);
  float bq = block_reduce_sum(qrow[0] + qrow[1], lds_red);
  if (tid == 0) {
    atomicAdd(&dbl[0], (double)bs);
    atomicAdd(&dbl[1], (double)bq);
  }

  // loop-invariant swizzled fragment byte offsets (within a 2048-B half)
  int offH0 = lrow * 128 + (((lk    ) ^ (lrow & 7)) << 4);
  int offH1 = lrow * 128 + (((lk + 4) ^ (lrow & 7)) << 4);

  const char* kst_b = (const char*)kst;
  const char* kk_b  = (const char*)kk2n;

  // prologue: stage step 0 into buffer 0 (4 x GLL16/thread + kk by wave 0)
  {
    char* ldst = &smem[0][0];
    #pragma unroll
    for (int c = 0; c < 4; ++c)
      GLL16(kst_b + c * 4096 + tid * 16, ldst + c * 4096 + tid * 16);
    if (wid == 0) GLL4(kk_b + lane * 4, ldst + 16384 + lane * 4);
  }

  float b1[2], b2[2];
  uint32_t j1[2];
  #pragma unroll
  for (int g = 0; g < 2; ++g) {
    b1[g] = -3.402823466e38f; b2[g] = -3.402823466e38f; j1[g] = 0;
  }

  for (int t = 0; t < 32; ++t) {
    __syncthreads();   // stage(t) resident; all waves done reading buf[(t+1)&1]
    if (t + 1 < 32) {
      const char* gsrc = kst_b + (size_t)(t + 1) * 16384;
      char* ldst = &smem[(t + 1) & 1][0];
      #pragma unroll
      for (int c = 0; c < 4; ++c)
        GLL16(gsrc + c * 4096 + tid * 16, ldst + c * 4096 + tid * 16);
      if (wid == 0) GLL4(kk_b + (size_t)(t + 1) * 256 + lane * 4, ldst + 16384 + lane * 4);
    }
    const char* B = &smem[t & 1][0];
    #pragma unroll
    for (int s = 0; s < 4; ++s) {
      bf16x8 ah0 = *(const bf16x8*)(B + s * 4096 + offH0);
      bf16x8 ah1 = *(const bf16x8*)(B + s * 4096 + offH1);
      bf16x8 al0 = *(const bf16x8*)(B + s * 4096 + 2048 + offH0);
      bf16x8 al1 = *(const bf16x8*)(B + s * 4096 + 2048 + offH1);
      f32x4 kkv  = *(const f32x4*)(B + 16384 + s * 64 + lk * 16);
      uint32_t jb = (uint32_t)(t * 64 + s * 16 + lk * 4);
      #pragma unroll
      for (int g = 0; g < 2; ++g) {
        f32x4 acc = __builtin_amdgcn_mfma_f32_16x16x32_bf16(ah0, xh[g][0], kkv, 0, 0, 0);
        acc = __builtin_amdgcn_mfma_f32_16x16x32_bf16(ah1, xh[g][1], acc, 0, 0, 0);
        acc = __builtin_amdgcn_mfma_f32_16x16x32_bf16(al0, xh[g][0], acc, 0, 0, 0);
        acc = __builtin_amdgcn_mfma_f32_16x16x32_bf16(al1, xh[g][1], acc, 0, 0, 0);
        acc = __builtin_amdgcn_mfma_f32_16x16x32_bf16(ah0, xl[g][0], acc, 0, 0, 0);
        acc = __builtin_amdgcn_mfma_f32_16x16x32_bf16(ah1, xl[g][1], acc, 0, 0, 0);
        #pragma unroll
        for (int reg = 0; reg < 4; ++reg) {
          float v = acc[reg];
          bool gt = v > b1[g];
          float mn = fminf(v, b1[g]);
          b2[g] = fmaxf(b2[g], mn);
          b1[g] = gt ? v : b1[g];
          j1[g] = gt ? (jb + (uint32_t)reg) : j1[g];
        }
      }
    }
  }

  // merge the 4 lanes (lane^16, lane^32) sharing one x-row; fused epilogue
  float cl_acc = 0.f;
  #pragma unroll
  for (int g = 0; g < 2; ++g) {
    float xxr = qrow[g];
    #pragma unroll
    for (int s = 16; s <= 32; s <<= 1) {
      float ob1 = __shfl_xor(b1[g], s, 64);
      float ob2 = __shfl_xor(b2[g], s, 64);
      uint32_t oj1 = __shfl_xor(j1[g], s, 64);
      xxr += __shfl_xor(xxr, s, 64);
      bool gt = ob1 > b1[g];
      float mn = fminf(b1[g], ob1);
      b2[g] = fmaxf(fmaxf(b2[g], ob2), mn);
      b1[g] = fmaxf(b1[g], ob1);
      j1[g] = gt ? oj1 : j1[g];
    }
    // all lanes now hold merged b1/b2/j1/xxr for their row (r0+g*16+lrow)
    int row = r0 + g * 16 + lrow;
    // x_d = korig[j1]: each lk lane writes 16 floats of the row
    {
      const float4* kp = (const float4*)(korig + (size_t)j1[g] * DIM + lk * 16);
      float4* xd = (float4*)(out + O_XD + (size_t)row * DIM + lk * 16);
      #pragma unroll
      for (int q = 0; q < 4; ++q) xd[q] = kp[q];
    }
    if (lk == 0) {
      xli[row] = (int)j1[g];
      out[O_XL + row] = (float)j1[g];
      cl_acc += fmaf(-2.f, b1[g], xxr);   // ||x-k||^2 = xx - 2*score
      if (b1[g] - b2[g] < 0.01f) {  // score gap = dist gap / 2
        int i = atomicAdd(cnt, 1);
        flag[i] = (uint32_t)row;
      }
    }
  }
  float bc = block_reduce_sum(cl_acc, lds_red);
  if (tid == 0) atomicAdd(&dbl[2], (double)bc);
}

// exact fp64 full rescan for near-tie rows; one wave per row.
// Also fixes up x_d / x_l / fit-sum for corrected rows (k_finish is fused away).
__global__ __launch_bounds__(256) void k_rescan(
    const uint32_t* __restrict__ flag, const int* __restrict__ cnt,
    const float* __restrict__ x, const float* __restrict__ k,
    int* __restrict__ xli, float* __restrict__ out, double* __restrict__ dbl) {
  __shared__ float xs[4][64];
  int lane = threadIdx.x & 63;
  int wid = threadIdx.x >> 6;
  int gw = (blockIdx.x * blockDim.x + threadIdx.x) >> 6;
  int n = *cnt;
  for (int fi = gw; fi < n; fi += 1024) {
    int row = flag[fi];
    int jold = xli[row];
    xs[wid][lane] = x[(size_t)row * DIM + lane];  // wave-synchronous LDS
    double bd = 1e300;
    double eold = 0.0;
    int bj = 0;
    for (int j = lane; j < KB; j += 64) {
      const float* kr = k + (size_t)j * DIM;
      double e = 0.0;
      #pragma unroll
      for (int d = 0; d < DIM; ++d) {
        double diff = (double)xs[wid][d] - (double)kr[d];
        e = fma(diff, diff, e);
      }
      if (e < bd) { bd = e; bj = j; }
      if (j == jold) eold = e;
    }
    #pragma unroll
    for (int off = 32; off > 0; off >>= 1) {
      double od = __shfl_down(bd, off, 64);
      int oj = __shfl_down(bj, off, 64);
      eold += __shfl_down(eold, off, 64);
      if (od < bd || (od == bd && oj < bj)) { bd = od; bj = oj; }
    }
    int bjf = __shfl(bj, 0, 64);
    if (bjf != jold) {
      out[O_XD + (size_t)row * DIM + lane] = k[(size_t)bjf * DIM + lane];
      if (lane == 0) {
        xli[row] = bjf;
        out[O_XL + row] = (float)bjf;
        atomicAdd(&dbl[2], bd - eold);   // exact fit/commit correction
      }
    }
  }
}

// exact kcnt histogram, built AFTER rescan corrections
__global__ void k_hist_rows(const int* __restrict__ xli, int* __restrict__ kcnt) {
  int i = blockIdx.x * blockDim.x + threadIdx.x;
  atomicAdd(&kcnt[xli[i]], 1);
}

// ======================= segment sum via counting sort =======================

__global__ __launch_bounds__(1024) void k_scan_bins(const int* __restrict__ kcnt,
                                                    uint32_t* __restrict__ boffs) {
  __shared__ uint32_t part[1024];
  int tid = threadIdx.x;
  uint32_t c0 = (uint32_t)kcnt[2 * tid];
  uint32_t c1 = (uint32_t)kcnt[2 * tid + 1];
  part[tid] = c0 + c1;
  __syncthreads();
  for (int off = 1; off < 1024; off <<= 1) {
    uint32_t v = (tid >= off) ? part[tid - off] : 0u;
    __syncthreads();
    part[tid] += v;
    __syncthreads();
  }
  uint32_t run = (tid > 0) ? part[tid - 1] : 0u;
  boffs[2 * tid] = run;
  boffs[2 * tid + 1] = run + c0;
}

__global__ void k_scatter_rows(const int* __restrict__ xli, const uint32_t* __restrict__ boffs,
                               uint32_t* __restrict__ bcur, uint32_t* __restrict__ rowlist) {
  int i = blockIdx.x * blockDim.x + threadIdx.x;
  int b = xli[i];
  uint32_t pos = boffs[b] + atomicAdd(&bcur[b], 1u);
  rowlist[pos] = (uint32_t)i;
}

// equal-work segment sum: one wave per 16 rowlist positions; lane = dim column.
__global__ __launch_bounds__(256) void k_segsum(
    const uint32_t* __restrict__ rowlist, const int* __restrict__ xli,
    const float* __restrict__ x, double* __restrict__ ks64) {
  int gw = (blockIdx.x * blockDim.x + threadIdx.x) >> 6;  // 8192 waves
  int lane = threadIdx.x & 63;
  uint32_t p0 = (uint32_t)gw * 16;
  double acc = 0.0;
  int cur = -1;
  #pragma unroll 4
  for (int i = 0; i < 16; ++i) {
    uint32_t row = rowlist[p0 + i];
    int bin = xli[row];
    if (bin != cur) {
      if (cur >= 0) atomicAdd(&ks64[(size_t)cur * DIM + lane], acc);
      acc = 0.0; cur = bin;
    }
    acc += (double)x[(size_t)row * DIM + lane];
  }
  if (cur >= 0) atomicAdd(&ks64[(size_t)cur * DIM + lane], acc);
}

// ---- JAX threefry permutation replication (15-bit bucket sort x2) ----

__global__ void k_bits_hist(int which, uint32_t* __restrict__ bits,
                            uint32_t* __restrict__ hist) {
  uint32_t a0, a1, b0, b1;
  threefry2x32(0u, 42u, 0u, 2u, a0, b0);
  threefry2x32(0u, 42u, 1u, 3u, a1, b1);
  uint32_t k0, k1;
  if (which == 0) { k0 = b0; k1 = b1; }
  else {
    uint32_t c0, c1, d0, d1;
    threefry2x32(a0, a1, 0u, 2u, c0, d0);
    threefry2x32(a0, a1, 1u, 3u, c1, d1);
    k0 = d0; k1 = d1;
  }
  int i = blockIdx.x * blockDim.x + threadIdx.x;  // 65536 threads
  uint32_t y0, y1;
  threefry2x32(k0, k1, (uint32_t)i, (uint32_t)(i + 65536), y0, y1);
  bits[i] = y0;
  bits[i + 65536] = y1;
  atomicAdd(&hist[y0 >> 17], 1u);
  atomicAdd(&hist[y1 >> 17], 1u);
}

// local exclusive scan of 256 bins per block; in-place; block total -> bsum
__global__ __launch_bounds__(256) void k_scanA(uint32_t* __restrict__ hist,
                                               uint32_t* __restrict__ bsum) {
  __shared__ uint32_t sh[256];
  int tid = threadIdx.x;
  int bin = blockIdx.x * 256 + tid;
  uint32_t v = hist[bin];
  sh[tid] = v;
  __syncthreads();
  for (int off = 1; off < 256; off <<= 1) {
    uint32_t t = (tid >= off) ? sh[tid - off] : 0u;
    __syncthreads();
    sh[tid] += t;
    __syncthreads();
  }
  hist[bin] = sh[tid] - v;                 // exclusive local prefix
  if (tid == 255) bsum[blockIdx.x] = sh[tid];
}

__global__ void k_scanB(uint32_t* __restrict__ bsum) {  // 1 block, 128 threads
  __shared__ uint32_t sh[128];
  int tid = threadIdx.x;
  uint32_t v = bsum[tid];
  sh[tid] = v;
  __syncthreads();
  for (int off = 1; off < 128; off <<= 1) {
    uint32_t t = (tid >= off) ? sh[tid - off] : 0u;
    __syncthreads();
    sh[tid] += t;
    __syncthreads();
  }
  bsum[tid] = sh[tid] - v;  // exclusive
}

__global__ void k_scatter(const uint32_t* __restrict__ bits, const uint32_t* __restrict__ hist,
                          const uint32_t* __restrict__ bsum, uint32_t* __restrict__ cursor,
                          uint32_t* __restrict__ pkey, uint32_t* __restrict__ pidx) {
  int i = blockIdx.x * blockDim.x + threadIdx.x;
  uint32_t key = bits[i];
  uint32_t bin = key >> 17;
  uint32_t pos = hist[bin] + bsum[bin >> 8] + atomicAdd(&cursor[bin], 1u);
  pkey[pos] = key; pidx[pos] = (uint32_t)i;
}

// rank within bucket (stable). limit==0: write full res; else write first
// `limit` positions of the final permutation AND gather x rows into krand.
__global__ void k_rank(const uint32_t* __restrict__ pkey, const uint32_t* __restrict__ pidx,
                       const uint32_t* __restrict__ hist, const uint32_t* __restrict__ bsum,
                       const uint32_t* __restrict__ cursor,
                       const uint32_t* __restrict__ srcvals, uint32_t* __restrict__ outv,
                       const float* __restrict__ x, float* __restrict__ krand,
                       int limit) {
  int s = blockIdx.x * blockDim.x + threadIdx.x;
  uint32_t myk = pkey[s], myi = pidx[s];
  uint32_t bin = myk >> 17;
  uint32_t start = hist[bin] + bsum[bin >> 8], cntb = cursor[bin];
  uint32_t r = 0;
  for (uint32_t t = 0; t < cntb; ++t) {
    uint32_t ok = pkey[start + t], oi = pidx[start + t];
    r += (ok < myk || (ok == myk && oi < myi)) ? 1u : 0u;
  }
  uint32_t pos = start + r;
  if (limit == 0) {
    outv[pos] = myi;   // res1[i] = original index at round-1 sorted position i
  } else if (pos < (uint32_t)limit) {
    uint32_t orig = srcvals[myi];      // final perm value
    const float4* xs = (const float4*)(x + (size_t)orig * DIM);
    float4* kd = (float4*)(krand + (size_t)pos * DIM);
    #pragma unroll
    for (int q = 0; q < 16; ++q) kd[q] = xs[q];
  }
}

// ======================= EMA update + finale =======================

__global__ __launch_bounds__(256) void k_elem_kernel(
    const double* __restrict__ ks64, const int* __restrict__ kcnt,
    const float* __restrict__ k_sum_in, const float* __restrict__ k_elem_in,
    const float* __restrict__ k_in, const float* __restrict__ krand,
    float* __restrict__ out, double* __restrict__ dbl) {
  __shared__ float lds[8];
  const float OMF = (float)(1.0 - 0.99);
  int e = blockIdx.x * blockDim.x + threadIdx.x;
  int b = e >> 6;
  float part = (float)ks64[e];
  float nks = 0.99f * k_sum_in[e] + OMF * part;
  out[O_NKS + e] = nks;
  float cnt = (float)kcnt[b];
  float ke = 0.99f * k_elem_in[b] + OMF * cnt;
  float nk = (ke >= 1.f) ? (nks / ke) : krand[e];
  out[O_NK + e] = nk;
  float dd = nk - k_in[e];
  float bsum = block_reduce_sum(dd * dd, lds);
  if (threadIdx.x == 0) atomicAdd(&dbl[4], (double)bsum);
}

__global__ __launch_bounds__(1024) void k_finale(
    const int* __restrict__ kcnt, const float* __restrict__ k_elem_in,
    float* __restrict__ out, const double* __restrict__ dbl) {
  __shared__ float ent_l[1024];
  __shared__ int u1_l[1024], u2_l[1024];
  const float OMF = (float)(1.0 - 0.99);
  int tid = threadIdx.x;
  float ent = 0.f; int used = 0, usage = 0;
  #pragma unroll
  for (int t = 0; t < 2; ++t) {
    int b = tid + t * 1024;
    float cnt = (float)kcnt[b];
    float ke = 0.99f * k_elem_in[b] + OMF * cnt;
    out[O_NKE + b] = ke;
    float p = cnt * (1.f / 131072.f);
    ent -= p * logf(p + 1e-8f);
    used += (cnt >= 1.f) ? 1 : 0;
    usage += (ke >= 1.f) ? 1 : 0;
  }
  ent_l[tid] = ent; u1_l[tid] = used; u2_l[tid] = usage;
  __syncthreads();
  for (int off = 512; off > 0; off >>= 1) {
    if (tid < off) {
      ent_l[tid] += ent_l[tid + off];
      u1_l[tid] += u1_l[tid + off];
      u2_l[tid] += u2_l[tid + off];
    }
    __syncthreads();
  }
  if (tid == 0) {
    double M = (double)M_ELEMS;
    double sumS = dbl[0], sumQ = dbl[1];
    double var = (sumQ - sumS * sumS / M) / M;
    out[O_PRE] = (float)sqrt(var > 0.0 ? var : 0.0);
    out[O_FIT] = (float)(dbl[2] / (double)N_ROWS);
    out[O_CL]  = (float)(dbl[2] / M);
    out[O_DK]  = (float)sqrt(dbl[4] / (double)(KB * DIM));
    out[O_ENT] = ent_l[0];
    out[O_USED] = (float)u1_l[0];
    out[O_UTOT] = (float)u2_l[0];
  }
}

// ======================= launch =======================

extern "C" void kernel_launch(void* const* d_in, const int* in_sizes, int n_in,
                              void* d_out, int out_size, void* d_ws, size_t ws_size,
                              hipStream_t stream) {
  (void)in_sizes; (void)n_in; (void)out_size; (void)ws_size;
  const float* x      = (const float*)d_in[0];
  const float* k      = (const float*)d_in[1];
  const float* k_sum  = (const float*)d_in[2];
  const float* k_elem = (const float*)d_in[3];
  float* out = (float*)d_out;
  char* ws = (char*)d_ws;

  double*   dbl   = (double*)(ws + A_DBL);
  int*      cnt   = (int*)(ws + A_CNT);
  float*    kk2n  = (float*)(ws + A_KK2N);
  unsigned short* kst = (unsigned short*)(ws + A_KST);
  int*      xli   = (int*)(ws + A_XLI);
  int*      kcnt  = (int*)(ws + A_KCNT);
  uint32_t* bcur  = (uint32_t*)(ws + A_BCUR);
  float*    krand = (float*)(ws + A_KRAND);
  uint32_t* boffs = (uint32_t*)(ws + A_BOFF);
  uint32_t* flag  = (uint32_t*)(ws + A_FLAG);
  uint32_t* rowl  = (uint32_t*)(ws + A_ROWL);
  double*   ks64  = (double*)(ws + A_KS64);
  uint32_t* bits  = (uint32_t*)(ws + A_BITS);
  uint32_t* pkey  = (uint32_t*)(ws + A_PKEY);
  uint32_t* hist  = (uint32_t*)(ws + A_HIST);
  uint32_t* bsum  = (uint32_t*)(ws + A_BSUM);
  uint32_t* cur   = (uint32_t*)(ws + A_CUR);
  uint32_t* pidx  = (uint32_t*)(ws + A_PIDX);
  uint32_t* res1  = (uint32_t*)(ws + A_RES1);

  (void)hipMemsetAsync(ws + A_DBL, 0, 128, stream);        // dbl + cnt
  (void)hipMemsetAsync(ws + A_KCNT, 0, 16384, stream);     // kcnt + bcur
  (void)hipMemsetAsync(ws + A_KS64, 0, 1048576, stream);   // f64 accumulators

  k_prep<<<512, 256, 0, stream>>>(k, kst, kk2n);
  k_main<<<1024, 256, 0, stream>>>(x, k, kst, kk2n, xli, flag, cnt, out, dbl);
  k_rescan<<<256, 256, 0, stream>>>(flag, cnt, x, k, xli, out, dbl);

  // segment sum via counting sort + equal-work chunked accumulation
  k_hist_rows<<<512, 256, 0, stream>>>(xli, kcnt);
  k_scan_bins<<<1, 1024, 0, stream>>>(kcnt, boffs);
  k_scatter_rows<<<512, 256, 0, stream>>>(xli, boffs, bcur, rowl);
  k_segsum<<<2048, 256, 0, stream>>>(rowl, xli, x, ks64);

  // jax.random.permutation(key(42), 131072): 2 stable sort rounds
  (void)hipMemsetAsync(ws + A_HIST, 0, 262656, stream);    // hist + bsum + cur
  k_bits_hist<<<256, 256, 0, stream>>>(0, bits, hist);
  k_scanA<<<128, 256, 0, stream>>>(hist, bsum);
  k_scanB<<<1, 128, 0, stream>>>(bsum);
  k_scatter<<<512, 256, 0, stream>>>(bits, hist, bsum, cur, pkey, pidx);
  k_rank<<<512, 256, 0, stream>>>(pkey, pidx, hist, bsum, cur, nullptr, res1,
                                  nullptr, nullptr, 0);
  (void)hipMemsetAsync(ws + A_HIST, 0, 262656, stream);
  k_bits_hist<<<256, 256, 0, stream>>>(1, bits, hist);
  k_scanA<<<128, 256, 0, stream>>>(hist, bsum);
  k_scanB<<<1, 128, 0, stream>>>(bsum);
  k_scatter<<<512, 256, 0, stream>>>(bits, hist, bsum, cur, pkey, pidx);
  k_rank<<<512, 256, 0, stream>>>(pkey, pidx, hist, bsum, cur, res1, nullptr,
                                  x, krand, 2048);

  k_elem_kernel<<<512, 256, 0, stream>>>(ks64, kcnt, k_sum, k_elem, k, krand, out, dbl);
  k_finale<<<1, 1024, 0, stream>>>(kcnt, k_elem, out, dbl);
}

// Round 15
// 359.575 us; speedup vs baseline: 1.5117x; 1.0417x over previous
//
#include <hip/hip_runtime.h>
#include <stdint.h>

#define N_ROWS 131072
#define DIM 64
#define KB 2048
#define M_ELEMS 8388608  // N_ROWS*DIM

// ---- output offsets (float32 elements, concatenated in return order) ----
#define O_XL   0
#define O_XD   131072
#define O_CL   8519680
#define O_FIT  8519681
#define O_PRE  8519682
#define O_ENT  8519683
#define O_USED 8519684
#define O_UTOT 8519685
#define O_DK   8519686
#define O_NK   8519687
#define O_NKS  8650759
#define O_NKE  8781831

// ---- workspace byte offsets (<= 5267616, proven in r1) ----
// init-zeroed region [0, 1065088) -> ONE memset:
#define A_DBL   0         // doubles: [0]=sumS,[1]=sumQ,[2]=sum cl,[4]=dk acc
#define A_CNT   64        // rescan counter (int)
#define A_KCNT  128       // 2048 i32
#define A_BCUR  8320      // 2048 u32
#define A_KS64  16512     // 131072 f64 (1 MB, live until k_elem)
// persistent (no zeroing needed):
#define A_KK2N  1065088   // 2048 f32 : -0.5*|k|^2
#define A_KST   1073280   // 524288 B: pre-swizzled kh|kl tile images
#define A_XLI   1597568   // 131072 i32
#define A_KRAND 2121856   // 131072 f32
#define A_BOFF  2646144   // 2048 u32
#define A_FLAG  2654336   // 131072 u32 (dead after k_rescan)
#define A_ROWL  3178624   // 131072 u32 (dead after k_segsum)
// RNG phase overlays FLAG/ROWL (temporally disjoint):
#define A_BITS  2654336   // 131072 u32 (overlays FLAG)
#define A_PKEY  3178624   // 131072 u32 (overlays ROWL)
#define A_HIST  3702912   // 32768 u32
#define A_BSUM  3833984   // 128 u32 (pad 512)
#define A_CUR   3834496   // 32768 u32   [HIST..CUR contiguous: one memset 262656]
#define A_PIDX  3965568   // 131072 u32
#define A_RES1  4489856   // 131072 u32
#define WS_END  5014144   // < 5267616 ok

typedef short bf16x8 __attribute__((ext_vector_type(8)));
typedef float f32x4 __attribute__((ext_vector_type(4)));

#define GLL16(G, L) __builtin_amdgcn_global_load_lds( \
    (const __attribute__((address_space(1))) void*)(G), \
    (__attribute__((address_space(3))) void*)(L), 16, 0, 0)
#define GLL4(G, L) __builtin_amdgcn_global_load_lds( \
    (const __attribute__((address_space(1))) void*)(G), \
    (__attribute__((address_space(3))) void*)(L), 4, 0, 0)

// ======================= helpers =======================

__device__ __forceinline__ float block_reduce_sum(float v, float* lds) {
  #pragma unroll
  for (int off = 32; off > 0; off >>= 1) v += __shfl_down(v, off, 64);
  int lane = threadIdx.x & 63, wid = threadIdx.x >> 6;
  if (lane == 0) lds[wid] = v;
  __syncthreads();
  float r = 0.f;
  if (threadIdx.x == 0) {
    int nw = blockDim.x >> 6;
    for (int i = 0; i < nw; ++i) r += lds[i];
  }
  __syncthreads();
  return r;  // valid on thread 0
}

__device__ __forceinline__ unsigned short f2bf_rne(float f) {
  uint32_t u = __float_as_uint(f);
  uint32_t r = u + 0x7FFFu + ((u >> 16) & 1u);
  return (unsigned short)(r >> 16);
}

#define TF_ROUND(r) do { x0 += x1; x1 = (x1 << (r)) | (x1 >> (32 - (r))); x1 ^= x0; } while (0)

__device__ __forceinline__ void threefry2x32(uint32_t k0, uint32_t k1,
                                             uint32_t c0, uint32_t c1,
                                             uint32_t& o0, uint32_t& o1) {
  uint32_t k2 = k0 ^ k1 ^ 0x1BD11BDAu;
  uint32_t x0 = c0 + k0, x1 = c1 + k1;
  TF_ROUND(13); TF_ROUND(15); TF_ROUND(26); TF_ROUND(6);
  x0 += k1; x1 += k2 + 1u;
  TF_ROUND(17); TF_ROUND(29); TF_ROUND(16); TF_ROUND(24);
  x0 += k2; x1 += k0 + 2u;
  TF_ROUND(13); TF_ROUND(15); TF_ROUND(26); TF_ROUND(6);
  x0 += k0; x1 += k1 + 3u;
  TF_ROUND(17); TF_ROUND(29); TF_ROUND(16); TF_ROUND(24);
  x0 += k1; x1 += k2 + 4u;
  TF_ROUND(13); TF_ROUND(15); TF_ROUND(26); TF_ROUND(6);
  x0 += k2; x1 += k0 + 5u;
  o0 = x0; o1 = x1;
}

// shared helper: exclusive 128-entry bsum scan done redundantly per block
// (replaces the dedicated k_scanB dispatch). sb[] must be 128 u32 LDS.
__device__ __forceinline__ void local_bsum_scan(const uint32_t* __restrict__ bsum,
                                                uint32_t* sb) {
  int tid = threadIdx.x;
  if (tid < 128) sb[tid] = bsum[tid];
  __syncthreads();
  for (int off = 1; off < 128; off <<= 1) {
    uint32_t t = (tid < 128 && tid >= off) ? sb[tid - off] : 0u;
    __syncthreads();
    if (tid < 128) sb[tid] += t;   // inclusive
    __syncthreads();
  }
}
// exclusive value for block index b: (b ? sb[b-1] : 0)

// ======================= codebook prep =======================
// one wave per code row. Writes the PRE-SWIZZLED kh|kl tile image so that
// a linear global_load_lds produces bank-spread ds_read_b128 fragments:
// tile t (4096 B) = [kh 2048 B | kl 2048 B]; within each half, (code r, dim d)
// lives at byte r*128 + (((d>>3) ^ (r&7))<<4) + (d&7)*2.
__global__ __launch_bounds__(256) void k_prep(
    const float* __restrict__ k, unsigned short* __restrict__ kst,
    float* __restrict__ kk2n) {
  int w = (blockIdx.x * blockDim.x + threadIdx.x) >> 6;  // code j, 2048 waves
  int lane = threadIdx.x & 63;                           // dim d
  float v = k[(size_t)w * DIM + lane];
  unsigned short h = f2bf_rne(v);
  float hf = __uint_as_float((uint32_t)h << 16);
  unsigned short lo = f2bf_rne(v - hf);
  int t = w >> 4, r = w & 15;
  int c = lane >> 3, e = lane & 7;
  int slot = c ^ (r & 7);
  size_t u16i = (size_t)t * 2048 + r * 64 + slot * 8 + e;
  kst[u16i] = h;           // kh half
  kst[u16i + 1024] = lo;   // kl half (+2048 B)
  float q = v * v;
  #pragma unroll
  for (int off = 32; off > 0; off >>= 1) q += __shfl_down(q, off, 64);
  if (lane == 0) kk2n[w] = -0.5f * q;
}

// ======================= MFMA argmin (LDS-staged k, g=4, 2 blk/CU) ==========
// 256 threads = 4 waves, g=4 (64 rows/wave, 256 rows/block), 512 blocks.
// 64-code staging steps (16.6 KB x2, double-buffered), ONE barrier per step:
//   barrier -> issue stage(t+1) -> [setprio(1)] compute buf[t&1] [setprio(0)]
// Fused epilogue: xli + out[O_XL] + x_d gather-write + fit/commit cl sum
// (cl = xx - 2*score), prenorm sums, tie-flag. (r13 g=4 shape: LDS reads/CU
// are half of g=2 -> measured faster; r14's g=2@4blk regressed.)
__global__ __launch_bounds__(256) void k_main(
    const float* __restrict__ x, const float* __restrict__ korig,
    const unsigned short* __restrict__ kst, const float* __restrict__ kk2n,
    int* __restrict__ xli, uint32_t* __restrict__ flag, int* __restrict__ cnt,
    float* __restrict__ out, double* __restrict__ dbl) {
  __shared__ __align__(16) char smem[2][16640];   // 16384 frag + 256 kk each
  __shared__ float lds_red[4];
  int tid = threadIdx.x;
  int lane = tid & 63;
  int wid = tid >> 6;           // 0..3
  int lrow = lane & 15;
  int lk = lane >> 4;           // 0..3
  int r0 = (blockIdx.x * 4 + wid) * 64;   // 64 rows per wave

  // load + decompose x fragments: 4 row-groups x 2 K-halves
  bf16x8 xh[4][2], xl[4][2];
  float qrow[4] = {0.f, 0.f, 0.f, 0.f};
  float s_acc = 0.f;
  #pragma unroll
  for (int g = 0; g < 4; ++g) {
    #pragma unroll
    for (int kt = 0; kt < 2; ++kt) {
      const float* xp = x + (size_t)(r0 + g * 16 + lrow) * DIM + kt * 32 + lk * 8;
      float4 v0 = *(const float4*)xp;
      float4 v1 = *(const float4*)(xp + 4);
      float vv[8] = {v0.x, v0.y, v0.z, v0.w, v1.x, v1.y, v1.z, v1.w};
      #pragma unroll
      for (int i = 0; i < 8; ++i) {
        float v = vv[i];
        s_acc += v;
        qrow[g] = fmaf(v, v, qrow[g]);
        unsigned short h = f2bf_rne(v);
        float hf = __uint_as_float((uint32_t)h << 16);
        xh[g][kt][i] = (short)h;
        xl[g][kt][i] = (short)f2bf_rne(v - hf);
      }
    }
  }
  // prenorm partial sums (x loaded exactly once grid-wide)
  float bs = block_reduce_sum(s_acc, lds_red);
  float bq = block_reduce_sum(qrow[0] + qrow[1] + qrow[2] + qrow[3], lds_red);
  if (tid == 0) {
    atomicAdd(&dbl[0], (double)bs);
    atomicAdd(&dbl[1], (double)bq);
  }

  // loop-invariant swizzled fragment byte offsets (within a 2048-B half)
  int offH0 = lrow * 128 + (((lk    ) ^ (lrow & 7)) << 4);
  int offH1 = lrow * 128 + (((lk + 4) ^ (lrow & 7)) << 4);

  const char* kst_b = (const char*)kst;
  const char* kk_b  = (const char*)kk2n;

  // prologue: stage step 0 into buffer 0 (4 x GLL16/thread + kk by wave 0)
  {
    char* ldst = &smem[0][0];
    #pragma unroll
    for (int c = 0; c < 4; ++c)
      GLL16(kst_b + c * 4096 + tid * 16, ldst + c * 4096 + tid * 16);
    if (wid == 0) GLL4(kk_b + lane * 4, ldst + 16384 + lane * 4);
  }

  float b1[4], b2[4];
  uint32_t j1[4];
  #pragma unroll
  for (int g = 0; g < 4; ++g) {
    b1[g] = -3.402823466e38f; b2[g] = -3.402823466e38f; j1[g] = 0;
  }

  for (int t = 0; t < 32; ++t) {
    __syncthreads();   // stage(t) resident; all waves done reading buf[(t+1)&1]
    if (t + 1 < 32) {
      const char* gsrc = kst_b + (size_t)(t + 1) * 16384;
      char* ldst = &smem[(t + 1) & 1][0];
      #pragma unroll
      for (int c = 0; c < 4; ++c)
        GLL16(gsrc + c * 4096 + tid * 16, ldst + c * 4096 + tid * 16);
      if (wid == 0) GLL4(kk_b + (size_t)(t + 1) * 256 + lane * 4, ldst + 16384 + lane * 4);
    }
    const char* B = &smem[t & 1][0];
    __builtin_amdgcn_s_setprio(1);
    #pragma unroll
    for (int s = 0; s < 4; ++s) {
      bf16x8 ah0 = *(const bf16x8*)(B + s * 4096 + offH0);
      bf16x8 ah1 = *(const bf16x8*)(B + s * 4096 + offH1);
      bf16x8 al0 = *(const bf16x8*)(B + s * 4096 + 2048 + offH0);
      bf16x8 al1 = *(const bf16x8*)(B + s * 4096 + 2048 + offH1);
      f32x4 kkv  = *(const f32x4*)(B + 16384 + s * 64 + lk * 16);
      uint32_t jb = (uint32_t)(t * 64 + s * 16 + lk * 4);
      #pragma unroll
      for (int g = 0; g < 4; ++g) {
        f32x4 acc = __builtin_amdgcn_mfma_f32_16x16x32_bf16(ah0, xh[g][0], kkv, 0, 0, 0);
        acc = __builtin_amdgcn_mfma_f32_16x16x32_bf16(ah1, xh[g][1], acc, 0, 0, 0);
        acc = __builtin_amdgcn_mfma_f32_16x16x32_bf16(al0, xh[g][0], acc, 0, 0, 0);
        acc = __builtin_amdgcn_mfma_f32_16x16x32_bf16(al1, xh[g][1], acc, 0, 0, 0);
        acc = __builtin_amdgcn_mfma_f32_16x16x32_bf16(ah0, xl[g][0], acc, 0, 0, 0);
        acc = __builtin_amdgcn_mfma_f32_16x16x32_bf16(ah1, xl[g][1], acc, 0, 0, 0);
        #pragma unroll
        for (int reg = 0; reg < 4; ++reg) {
          float v = acc[reg];
          bool gt = v > b1[g];
          float mn = fminf(v, b1[g]);
          b2[g] = fmaxf(b2[g], mn);
          b1[g] = gt ? v : b1[g];
          j1[g] = gt ? (jb + (uint32_t)reg) : j1[g];
        }
      }
    }
    __builtin_amdgcn_s_setprio(0);
  }

  // merge the 4 lanes (lane^16, lane^32) sharing one x-row; fused epilogue
  float cl_acc = 0.f;
  #pragma unroll
  for (int g = 0; g < 4; ++g) {
    float xxr = qrow[g];
    #pragma unroll
    for (int s = 16; s <= 32; s <<= 1) {
      float ob1 = __shfl_xor(b1[g], s, 64);
      float ob2 = __shfl_xor(b2[g], s, 64);
      uint32_t oj1 = __shfl_xor(j1[g], s, 64);
      xxr += __shfl_xor(xxr, s, 64);
      bool gt = ob1 > b1[g];
      float mn = fminf(b1[g], ob1);
      b2[g] = fmaxf(fmaxf(b2[g], ob2), mn);
      b1[g] = fmaxf(b1[g], ob1);
      j1[g] = gt ? oj1 : j1[g];
    }
    // all lanes now hold merged b1/b2/j1/xxr for their row (r0+g*16+lrow)
    int row = r0 + g * 16 + lrow;
    // x_d = korig[j1]: each lk lane writes 16 floats of the row
    {
      const float4* kp = (const float4*)(korig + (size_t)j1[g] * DIM + lk * 16);
      float4* xd = (float4*)(out + O_XD + (size_t)row * DIM + lk * 16);
      #pragma unroll
      for (int q = 0; q < 4; ++q) xd[q] = kp[q];
    }
    if (lk == 0) {
      xli[row] = (int)j1[g];
      out[O_XL + row] = (float)j1[g];
      cl_acc += fmaf(-2.f, b1[g], xxr);   // ||x-k||^2 = xx - 2*score
      if (b1[g] - b2[g] < 0.01f) {  // score gap = dist gap / 2
        int i = atomicAdd(cnt, 1);
        flag[i] = (uint32_t)row;
      }
    }
  }
  float bc = block_reduce_sum(cl_acc, lds_red);
  if (tid == 0) atomicAdd(&dbl[2], (double)bc);
}

// exact fp64 full rescan for near-tie rows; one wave per row.
// Also fixes up x_d / x_l / fit-sum for corrected rows.
__global__ __launch_bounds__(256) void k_rescan(
    const uint32_t* __restrict__ flag, const int* __restrict__ cnt,
    const float* __restrict__ x, const float* __restrict__ k,
    int* __restrict__ xli, float* __restrict__ out, double* __restrict__ dbl) {
  __shared__ float xs[4][64];
  int lane = threadIdx.x & 63;
  int wid = threadIdx.x >> 6;
  int gw = (blockIdx.x * blockDim.x + threadIdx.x) >> 6;
  int n = *cnt;
  for (int fi = gw; fi < n; fi += 1024) {
    int row = flag[fi];
    int jold = xli[row];
    xs[wid][lane] = x[(size_t)row * DIM + lane];  // wave-synchronous LDS
    double bd = 1e300;
    double eold = 0.0;
    int bj = 0;
    for (int j = lane; j < KB; j += 64) {
      const float* kr = k + (size_t)j * DIM;
      double e = 0.0;
      #pragma unroll
      for (int d = 0; d < DIM; ++d) {
        double diff = (double)xs[wid][d] - (double)kr[d];
        e = fma(diff, diff, e);
      }
      if (e < bd) { bd = e; bj = j; }
      if (j == jold) eold = e;
    }
    #pragma unroll
    for (int off = 32; off > 0; off >>= 1) {
      double od = __shfl_down(bd, off, 64);
      int oj = __shfl_down(bj, off, 64);
      eold += __shfl_down(eold, off, 64);
      if (od < bd || (od == bd && oj < bj)) { bd = od; bj = oj; }
    }
    int bjf = __shfl(bj, 0, 64);
    if (bjf != jold) {
      out[O_XD + (size_t)row * DIM + lane] = k[(size_t)bjf * DIM + lane];
      if (lane == 0) {
        xli[row] = bjf;
        out[O_XL + row] = (float)bjf;
        atomicAdd(&dbl[2], bd - eold);   // exact fit/commit correction
      }
    }
  }
}

// exact kcnt histogram, built AFTER rescan corrections
__global__ void k_hist_rows(const int* __restrict__ xli, int* __restrict__ kcnt) {
  int i = blockIdx.x * blockDim.x + threadIdx.x;
  atomicAdd(&kcnt[xli[i]], 1);
}

// ======================= segment sum via counting sort =======================

__global__ __launch_bounds__(1024) void k_scan_bins(const int* __restrict__ kcnt,
                                                    uint32_t* __restrict__ boffs) {
  __shared__ uint32_t part[1024];
  int tid = threadIdx.x;
  uint32_t c0 = (uint32_t)kcnt[2 * tid];
  uint32_t c1 = (uint32_t)kcnt[2 * tid + 1];
  part[tid] = c0 + c1;
  __syncthreads();
  for (int off = 1; off < 1024; off <<= 1) {
    uint32_t v = (tid >= off) ? part[tid - off] : 0u;
    __syncthreads();
    part[tid] += v;
    __syncthreads();
  }
  uint32_t run = (tid > 0) ? part[tid - 1] : 0u;
  boffs[2 * tid] = run;
  boffs[2 * tid + 1] = run + c0;
}

__global__ void k_scatter_rows(const int* __restrict__ xli, const uint32_t* __restrict__ boffs,
                               uint32_t* __restrict__ bcur, uint32_t* __restrict__ rowlist) {
  int i = blockIdx.x * blockDim.x + threadIdx.x;
  int b = xli[i];
  uint32_t pos = boffs[b] + atomicAdd(&bcur[b], 1u);
  rowlist[pos] = (uint32_t)i;
}

// equal-work segment sum: one wave per 16 rowlist positions; lane = dim column.
__global__ __launch_bounds__(256) void k_segsum(
    const uint32_t* __restrict__ rowlist, const int* __restrict__ xli,
    const float* __restrict__ x, double* __restrict__ ks64) {
  int gw = (blockIdx.x * blockDim.x + threadIdx.x) >> 6;  // 8192 waves
  int lane = threadIdx.x & 63;
  uint32_t p0 = (uint32_t)gw * 16;
  double acc = 0.0;
  int cur = -1;
  #pragma unroll 4
  for (int i = 0; i < 16; ++i) {
    uint32_t row = rowlist[p0 + i];
    int bin = xli[row];
    if (bin != cur) {
      if (cur >= 0) atomicAdd(&ks64[(size_t)cur * DIM + lane], acc);
      acc = 0.0; cur = bin;
    }
    acc += (double)x[(size_t)row * DIM + lane];
  }
  if (cur >= 0) atomicAdd(&ks64[(size_t)cur * DIM + lane], acc);
}

// ---- JAX threefry permutation replication (15-bit bucket sort x2) ----

__global__ void k_bits_hist(int which, uint32_t* __restrict__ bits,
                            uint32_t* __restrict__ hist) {
  uint32_t a0, a1, b0, b1;
  threefry2x32(0u, 42u, 0u, 2u, a0, b0);
  threefry2x32(0u, 42u, 1u, 3u, a1, b1);
  uint32_t k0, k1;
  if (which == 0) { k0 = b0; k1 = b1; }
  else {
    uint32_t c0, c1, d0, d1;
    threefry2x32(a0, a1, 0u, 2u, c0, d0);
    threefry2x32(a0, a1, 1u, 3u, c1, d1);
    k0 = d0; k1 = d1;
  }
  int i = blockIdx.x * blockDim.x + threadIdx.x;  // 65536 threads
  uint32_t y0, y1;
  threefry2x32(k0, k1, (uint32_t)i, (uint32_t)(i + 65536), y0, y1);
  bits[i] = y0;
  bits[i + 65536] = y1;
  atomicAdd(&hist[y0 >> 17], 1u);
  atomicAdd(&hist[y1 >> 17], 1u);
}

// local exclusive scan of 256 bins per block; in-place; block total -> bsum
__global__ __launch_bounds__(256) void k_scanA(uint32_t* __restrict__ hist,
                                               uint32_t* __restrict__ bsum) {
  __shared__ uint32_t sh[256];
  int tid = threadIdx.x;
  int bin = blockIdx.x * 256 + tid;
  uint32_t v = hist[bin];
  sh[tid] = v;
  __syncthreads();
  for (int off = 1; off < 256; off <<= 1) {
    uint32_t t = (tid >= off) ? sh[tid - off] : 0u;
    __syncthreads();
    sh[tid] += t;
    __syncthreads();
  }
  hist[bin] = sh[tid] - v;                 // exclusive local prefix
  if (tid == 255) bsum[blockIdx.x] = sh[tid];
}

// scatter with redundant in-block bsum scan (k_scanB dispatch eliminated)
__global__ __launch_bounds__(256) void k_scatter(
    const uint32_t* __restrict__ bits, const uint32_t* __restrict__ hist,
    const uint32_t* __restrict__ bsum, uint32_t* __restrict__ cursor,
    uint32_t* __restrict__ pkey, uint32_t* __restrict__ pidx) {
  __shared__ uint32_t sb[128];
  local_bsum_scan(bsum, sb);
  int i = blockIdx.x * blockDim.x + threadIdx.x;
  uint32_t key = bits[i];
  uint32_t bin = key >> 17;
  uint32_t blk = bin >> 8;
  uint32_t base = (blk ? sb[blk - 1] : 0u);
  uint32_t pos = hist[bin] + base + atomicAdd(&cursor[bin], 1u);
  pkey[pos] = key; pidx[pos] = (uint32_t)i;
}

// rank within bucket (stable), with redundant in-block bsum scan.
// limit==0: write full res; else write first `limit` positions of the final
// permutation AND gather x rows into krand.
__global__ __launch_bounds__(256) void k_rank(
    const uint32_t* __restrict__ pkey, const uint32_t* __restrict__ pidx,
    const uint32_t* __restrict__ hist, const uint32_t* __restrict__ bsum,
    const uint32_t* __restrict__ cursor,
    const uint32_t* __restrict__ srcvals, uint32_t* __restrict__ outv,
    const float* __restrict__ x, float* __restrict__ krand,
    int limit) {
  __shared__ uint32_t sb[128];
  local_bsum_scan(bsum, sb);
  int s = blockIdx.x * blockDim.x + threadIdx.x;
  uint32_t myk = pkey[s], myi = pidx[s];
  uint32_t bin = myk >> 17;
  uint32_t blk = bin >> 8;
  uint32_t start = hist[bin] + (blk ? sb[blk - 1] : 0u);
  uint32_t cntb = cursor[bin];
  if (limit != 0 && start >= (uint32_t)limit) return;  // round-2 truncation
  uint32_t r = 0;
  for (uint32_t t = 0; t < cntb; ++t) {
    uint32_t ok = pkey[start + t], oi = pidx[start + t];
    r += (ok < myk || (ok == myk && oi < myi)) ? 1u : 0u;
  }
  uint32_t pos = start + r;
  if (limit == 0) {
    outv[pos] = myi;   // res1[i] = original index at round-1 sorted position i
  } else if (pos < (uint32_t)limit) {
    uint32_t orig = srcvals[myi];      // final perm value
    const float4* xs = (const float4*)(x + (size_t)orig * DIM);
    float4* kd = (float4*)(krand + (size_t)pos * DIM);
    #pragma unroll
    for (int q = 0; q < 16; ++q) kd[q] = xs[q];
  }
}

// ======================= EMA update + finale =======================

__global__ __launch_bounds__(256) void k_elem_kernel(
    const double* __restrict__ ks64, const int* __restrict__ kcnt,
    const float* __restrict__ k_sum_in, const float* __restrict__ k_elem_in,
    const float* __restrict__ k_in, const float* __restrict__ krand,
    float* __restrict__ out, double* __restrict__ dbl) {
  __shared__ float lds[8];
  const float OMF = (float)(1.0 - 0.99);
  int e = blockIdx.x * blockDim.x + threadIdx.x;
  int b = e >> 6;
  float part = (float)ks64[e];
  float nks = 0.99f * k_sum_in[e] + OMF * part;
  out[O_NKS + e] = nks;
  float cnt = (float)kcnt[b];
  float ke = 0.99f * k_elem_in[b] + OMF * cnt;
  float nk = (ke >= 1.f) ? (nks / ke) : krand[e];
  out[O_NK + e] = nk;
  float dd = nk - k_in[e];
  float bsum = block_reduce_sum(dd * dd, lds);
  if (threadIdx.x == 0) atomicAdd(&dbl[4], (double)bsum);
}

__global__ __launch_bounds__(1024) void k_finale(
    const int* __restrict__ kcnt, const float* __restrict__ k_elem_in,
    float* __restrict__ out, const double* __restrict__ dbl) {
  __shared__ float ent_l[1024];
  __shared__ int u1_l[1024], u2_l[1024];
  const float OMF = (float)(1.0 - 0.99);
  int tid = threadIdx.x;
  float ent = 0.f; int used = 0, usage = 0;
  #pragma unroll
  for (int t = 0; t < 2; ++t) {
    int b = tid + t * 1024;
    float cnt = (float)kcnt[b];
    float ke = 0.99f * k_elem_in[b] + OMF * cnt;
    out[O_NKE + b] = ke;
    float p = cnt * (1.f / 131072.f);
    ent -= p * logf(p + 1e-8f);
    used += (cnt >= 1.f) ? 1 : 0;
    usage += (ke >= 1.f) ? 1 : 0;
  }
  ent_l[tid] = ent; u1_l[tid] = used; u2_l[tid] = usage;
  __syncthreads();
  for (int off = 512; off > 0; off >>= 1) {
    if (tid < off) {
      ent_l[tid] += ent_l[tid + off];
      u1_l[tid] += u1_l[tid + off];
      u2_l[tid] += u2_l[tid + off];
    }
    __syncthreads();
  }
  if (tid == 0) {
    double M = (double)M_ELEMS;
    double sumS = dbl[0], sumQ = dbl[1];
    double var = (sumQ - sumS * sumS / M) / M;
    out[O_PRE] = (float)sqrt(var > 0.0 ? var : 0.0);
    out[O_FIT] = (float)(dbl[2] / (double)N_ROWS);
    out[O_CL]  = (float)(dbl[2] / M);
    out[O_DK]  = (float)sqrt(dbl[4] / (double)(KB * DIM));
    out[O_ENT] = ent_l[0];
    out[O_USED] = (float)u1_l[0];
    out[O_UTOT] = (float)u2_l[0];
  }
}

// ======================= launch =======================

extern "C" void kernel_launch(void* const* d_in, const int* in_sizes, int n_in,
                              void* d_out, int out_size, void* d_ws, size_t ws_size,
                              hipStream_t stream) {
  (void)in_sizes; (void)n_in; (void)out_size; (void)ws_size;
  const float* x      = (const float*)d_in[0];
  const float* k      = (const float*)d_in[1];
  const float* k_sum  = (const float*)d_in[2];
  const float* k_elem = (const float*)d_in[3];
  float* out = (float*)d_out;
  char* ws = (char*)d_ws;

  double*   dbl   = (double*)(ws + A_DBL);
  int*      cnt   = (int*)(ws + A_CNT);
  int*      kcnt  = (int*)(ws + A_KCNT);
  uint32_t* bcur  = (uint32_t*)(ws + A_BCUR);
  double*   ks64  = (double*)(ws + A_KS64);
  float*    kk2n  = (float*)(ws + A_KK2N);
  unsigned short* kst = (unsigned short*)(ws + A_KST);
  int*      xli   = (int*)(ws + A_XLI);
  float*    krand = (float*)(ws + A_KRAND);
  uint32_t* boffs = (uint32_t*)(ws + A_BOFF);
  uint32_t* flag  = (uint32_t*)(ws + A_FLAG);
  uint32_t* rowl  = (uint32_t*)(ws + A_ROWL);
  uint32_t* bits  = (uint32_t*)(ws + A_BITS);
  uint32_t* pkey  = (uint32_t*)(ws + A_PKEY);
  uint32_t* hist  = (uint32_t*)(ws + A_HIST);
  uint32_t* bsum  = (uint32_t*)(ws + A_BSUM);
  uint32_t* cur   = (uint32_t*)(ws + A_CUR);
  uint32_t* pidx  = (uint32_t*)(ws + A_PIDX);
  uint32_t* res1  = (uint32_t*)(ws + A_RES1);

  // ONE init memset: dbl+cnt+kcnt+bcur+ks64 contiguous [0, 1065088)
  (void)hipMemsetAsync(ws, 0, 1065088, stream);

  k_prep<<<512, 256, 0, stream>>>(k, kst, kk2n);
  k_main<<<512, 256, 0, stream>>>(x, k, kst, kk2n, xli, flag, cnt, out, dbl);
  k_rescan<<<256, 256, 0, stream>>>(flag, cnt, x, k, xli, out, dbl);

  // segment sum via counting sort + equal-work chunked accumulation
  k_hist_rows<<<512, 256, 0, stream>>>(xli, kcnt);
  k_scan_bins<<<1, 1024, 0, stream>>>(kcnt, boffs);
  k_scatter_rows<<<512, 256, 0, stream>>>(xli, boffs, bcur, rowl);
  k_segsum<<<2048, 256, 0, stream>>>(rowl, xli, x, ks64);

  // jax.random.permutation(key(42), 131072): 2 stable sort rounds
  (void)hipMemsetAsync(ws + A_HIST, 0, 262656, stream);    // hist + bsum + cur
  k_bits_hist<<<256, 256, 0, stream>>>(0, bits, hist);
  k_scanA<<<128, 256, 0, stream>>>(hist, bsum);
  k_scatter<<<512, 256, 0, stream>>>(bits, hist, bsum, cur, pkey, pidx);
  k_rank<<<512, 256, 0, stream>>>(pkey, pidx, hist, bsum, cur, nullptr, res1,
                                  nullptr, nullptr, 0);
  (void)hipMemsetAsync(ws + A_HIST, 0, 262656, stream);
  k_bits_hist<<<256, 256, 0, stream>>>(1, bits, hist);
  k_scanA<<<128, 256, 0, stream>>>(hist, bsum);
  k_scatter<<<512, 256, 0, stream>>>(bits, hist, bsum, cur, pkey, pidx);
  k_rank<<<512, 256, 0, stream>>>(pkey, pidx, hist, bsum, cur, res1, nullptr,
                                  x, krand, 2048);

  k_elem_kernel<<<512, 256, 0, stream>>>(ks64, kcnt, k_sum, k_elem, k, krand, out, dbl);
  k_finale<<<1, 1024, 0, stream>>>(kcnt, k_elem, out, dbl);
}